// Round 9
// baseline (504.037 us; speedup 1.0000x reference)
//
#include <hip/hip_runtime.h>
#include <math.h>

typedef unsigned short ushort_t;

// ---------- helpers ----------

__device__ inline unsigned fenc(float f) {
    unsigned u = __float_as_uint(f);
    return (u & 0x80000000u) ? ~u : (u | 0x80000000u);
}
__device__ inline float fdec(unsigned u) {
    return __uint_as_float((u & 0x80000000u) ? (u ^ 0x80000000u) : ~u);
}

__device__ inline float wrsum(float v) {
    #pragma unroll
    for (int m = 32; m; m >>= 1) v += __shfl_xor(v, m, 64);
    return v;
}
__device__ inline float wrmax(float v) {
    #pragma unroll
    for (int m = 32; m; m >>= 1) v = fmaxf(v, __shfl_xor(v, m, 64));
    return v;
}
__device__ inline float lrelu(float x) { return x > 0.f ? x : 0.2f * x; }

__device__ inline ushort_t f2bf(float f) {
    unsigned u = __float_as_uint(f);
    u += 0x7FFFu + ((u >> 16) & 1u);      // round-to-nearest-even
    return (ushort_t)(u >> 16);
}
__device__ inline float bflo(unsigned u) { return __uint_as_float(u << 16); }
__device__ inline float bfhi(unsigned u) { return __uint_as_float(u & 0xFFFF0000u); }

// ---------- GEMM 1 + fused scores1.  h1b[n][dd][h] permuted bf16 layout ----------
// x is read via wave-uniform addresses -> scalar (s_load) path, no LDS staging.
__global__ __launch_bounds__(256) void gemm1_kernel(const float* __restrict__ x,
                                                    const float* __restrict__ W,
                                                    const float* __restrict__ a_src,
                                                    const float* __restrict__ a_dst,
                                                    ushort_t* __restrict__ h1b,
                                                    float* __restrict__ ssrc,
                                                    float* __restrict__ sdst, int N) {
    __shared__ float ss[16 * 257];      // acc transpose for score reduction
    __shared__ float ps[256];           // score partials
    int base = blockIdx.x * 16;
    int tid = threadIdx.x;
    float acc[16];
    #pragma unroll
    for (int j = 0; j < 16; j++) acc[j] = 0.f;

    if (base + 16 <= N) {
        for (int k = 0; k < 128; k += 4) {
            float w0 = W[k * 256 + tid];
            float w1 = W[(k + 1) * 256 + tid];
            float w2 = W[(k + 2) * 256 + tid];
            float w3 = W[(k + 3) * 256 + tid];
            #pragma unroll
            for (int j = 0; j < 16; j++) {
                float4 xj = *(const float4*)(x + (size_t)(base + j) * 128 + k);  // uniform -> s_load
                acc[j] += xj.x * w0 + xj.y * w1 + xj.z * w2 + xj.w * w3;
            }
        }
    } else {
        for (int k = 0; k < 128; k += 4) {
            float w0 = W[k * 256 + tid];
            float w1 = W[(k + 1) * 256 + tid];
            float w2 = W[(k + 2) * 256 + tid];
            float w3 = W[(k + 3) * 256 + tid];
            #pragma unroll
            for (int j = 0; j < 16; j++) {
                if (base + j < N) {
                    float4 xj = *(const float4*)(x + (size_t)(base + j) * 128 + k);
                    acc[j] += xj.x * w0 + xj.y * w1 + xj.z * w2 + xj.w * w3;
                }
            }
        }
    }
    int dd = tid & 63, hh = tid >> 6;
    #pragma unroll
    for (int j = 0; j < 16; j++) {
        int n = base + j;
        if (n < N) h1b[(size_t)n * 256 + dd * 4 + hh] = f2bf(acc[j]);
    }
    // ---- scores via LDS transpose + partial sums (hh2-rotated to kill bank conflicts) ----
    #pragma unroll
    for (int j = 0; j < 16; j++) ss[j * 257 + tid] = acc[j];
    __syncthreads();
    int j = tid & 15, hh2 = (tid >> 4) & 3, which = (tid >> 6) & 1, half = tid >> 7;
    const float* av = which ? a_dst : a_src;
    int cbase = hh2 * 64 + half * 32;
    float sum = 0.f;
    #pragma unroll
    for (int i = 0; i < 32; i++) {
        int ii = (i + 8 * hh2) & 31;       // rotate start per hh2 -> 2 lanes/bank (free)
        sum += ss[j * 257 + cbase + ii] * av[cbase + ii];
    }
    ps[tid] = sum;
    __syncthreads();
    if (half == 0) {
        float tot = sum + ps[tid + 128];
        int n = base + j;
        if (n < N) (which ? sdst : ssrc)[n * 4 + hh2] = tot;
    }
}

// ---------- CSR build ----------
__global__ __launch_bounds__(256) void hist_kernel(const int* __restrict__ ei,
                                                   int* __restrict__ deg, int E, int Etot) {
    int i = blockIdx.x * 256 + threadIdx.x;
    if (i >= Etot) return;
    int d = (i < E) ? ei[E + i] : (i - E);
    atomicAdd(&deg[d], 1);
}

__global__ __launch_bounds__(256) void chunksum_kernel(const int* __restrict__ deg,
                                                       int* __restrict__ csum, int M) {
    __shared__ int sm[256];
    int t = blockIdx.x * 256 + threadIdx.x;
    sm[threadIdx.x] = (t < M) ? deg[t] : 0;
    __syncthreads();
    for (int off = 128; off > 0; off >>= 1) {
        if (threadIdx.x < off) sm[threadIdx.x] += sm[threadIdx.x + off];
        __syncthreads();
    }
    if (threadIdx.x == 0) csum[blockIdx.x] = sm[0];
}

__global__ __launch_bounds__(256) void scanchunks_kernel(const int* __restrict__ csum,
                                                         int* __restrict__ coffset, int nchunks) {
    __shared__ int sm[256];
    int v = (threadIdx.x < nchunks) ? csum[threadIdx.x] : 0;
    sm[threadIdx.x] = v;
    __syncthreads();
    for (int off = 1; off < 256; off <<= 1) {
        int a = (threadIdx.x >= off) ? sm[threadIdx.x - off] : 0;
        __syncthreads();
        sm[threadIdx.x] += a;
        __syncthreads();
    }
    coffset[threadIdx.x] = sm[threadIdx.x] - v;
}

__global__ __launch_bounds__(256) void rowptr_kernel(const int* __restrict__ deg,
                                                     const int* __restrict__ coffset,
                                                     int* __restrict__ rowptr,
                                                     int* __restrict__ cursor, int M, int N) {
    __shared__ int sm[256];
    int t = blockIdx.x * 256 + threadIdx.x;
    int v = (t < M) ? deg[t] : 0;
    sm[threadIdx.x] = v;
    __syncthreads();
    for (int off = 1; off < 256; off <<= 1) {
        int a = (threadIdx.x >= off) ? sm[threadIdx.x - off] : 0;
        __syncthreads();
        sm[threadIdx.x] += a;
        __syncthreads();
    }
    if (t < M) {
        int rp = coffset[blockIdx.x] + sm[threadIdx.x] - v;
        rowptr[t] = rp;
        if (t < N) cursor[t] = rp;
    }
}

__global__ __launch_bounds__(256) void scatter_kernel(const int* __restrict__ ei,
                                                      int* __restrict__ cursor,
                                                      int* __restrict__ srcbuf, int E, int Etot) {
    int i = blockIdx.x * 256 + threadIdx.x;
    if (i >= Etot) return;
    int s, d;
    if (i < E) { s = ei[i]; d = ei[E + i]; } else { s = d = i - E; }
    int pos = atomicAdd(&cursor[d], 1);
    srcbuf[pos] = s;
}

// ---------- va/vb = W2 @ a_src2 / a_dst2 (folded layer-2 score vectors) ----------
__global__ __launch_bounds__(256) void vab_kernel(const float* __restrict__ W2,
                                                  const float* __restrict__ a_src2,
                                                  const float* __restrict__ a_dst2,
                                                  float* __restrict__ va,
                                                  float* __restrict__ vb) {
    int k = threadIdx.x;   // 256 threads = 256 rows of W2
    float sa = 0.f, sb = 0.f;
    #pragma unroll 8
    for (int c = 0; c < 64; c++) {
        float w = W2[k * 64 + c];
        sa += w * a_src2[c];
        sb += w * a_dst2[c];
    }
    va[k] = sa;
    vb[k] = sb;
}

// ---------- layer-1 aggregation: bf16 512B rows, 1 row/instr, inline softmax ----------
// epilogue: x2b (bf16) + layer-2 scores via folded va/vb
__global__ __launch_bounds__(256) void agg1_kernel(const int* __restrict__ rowptr,
                                                   const int* __restrict__ srcbuf,
                                                   const float* __restrict__ ssrc,
                                                   const float* __restrict__ sdst,
                                                   const ushort_t* __restrict__ h1b,
                                                   const float* __restrict__ b1,
                                                   const float* __restrict__ va,
                                                   const float* __restrict__ vb,
                                                   ushort_t* __restrict__ x2b,
                                                   float* __restrict__ ssrc2,
                                                   float* __restrict__ sdst2, int N) {
    __shared__ int    s_sh[4][64];
    __shared__ float4 w_sh[4][64];
    int lane = threadIdx.x & 63, w = threadIdx.x >> 6;
    int d = blockIdx.x * 4 + w;
    if (d >= N) return;
    int row = rowptr[d], end = rowptr[d + 1];
    float4 sd = *(const float4*)(sdst + d * 4);
    float m0 = -INFINITY, m1 = -INFINITY, m2 = -INFINITY, m3 = -INFINITY;
    float l0 = 0.f, l1 = 0.f, l2 = 0.f, l3 = 0.f;
    float a0 = 0.f, a1 = 0.f, a2 = 0.f, a3 = 0.f;

    for (int base = row; base < end; base += 64) {
        int cnt = min(64, end - base);
        bool valid = lane < cnt;
        int s = valid ? srcbuf[base + lane] : 0;
        float4 ssv = *(const float4*)(ssrc + s * 4);
        float e0 = ssv.x + sd.x, e1 = ssv.y + sd.y, e2 = ssv.z + sd.z, e3 = ssv.w + sd.w;
        e0 = lrelu(e0); e1 = lrelu(e1); e2 = lrelu(e2); e3 = lrelu(e3);
        if (!valid) { e0 = e1 = e2 = e3 = -INFINITY; }
        float nm0 = fmaxf(m0, wrmax(e0)), nm1 = fmaxf(m1, wrmax(e1));
        float nm2 = fmaxf(m2, wrmax(e2)), nm3 = fmaxf(m3, wrmax(e3));
        float sc0 = __expf(m0 - nm0), sc1 = __expf(m1 - nm1);
        float sc2 = __expf(m2 - nm2), sc3 = __expf(m3 - nm3);
        float w0 = __expf(e0 - nm0), w1 = __expf(e1 - nm1);
        float w2 = __expf(e2 - nm2), w3 = __expf(e3 - nm3);
        l0 = l0 * sc0 + wrsum(w0);  l1 = l1 * sc1 + wrsum(w1);
        l2 = l2 * sc2 + wrsum(w2);  l3 = l3 * sc3 + wrsum(w3);
        a0 *= sc0; a1 *= sc1; a2 *= sc2; a3 *= sc3;
        m0 = nm0; m1 = nm1; m2 = nm2; m3 = nm3;
        s_sh[w][lane] = s;
        w_sh[w][lane] = make_float4(w0, w1, w2, w3);
        // wave-private LDS; lockstep wave, no barrier needed
        int cnt4 = (cnt + 3) & ~3;
        for (int j = 0; j < cnt4; j += 4) {
            int sj0 = s_sh[w][j], sj1 = s_sh[w][j + 1], sj2 = s_sh[w][j + 2], sj3 = s_sh[w][j + 3];
            float4 wj0 = w_sh[w][j], wj1 = w_sh[w][j + 1], wj2 = w_sh[w][j + 2], wj3 = w_sh[w][j + 3];
            uint2 u0 = *(const uint2*)(h1b + (size_t)sj0 * 256 + lane * 4);
            uint2 u1 = *(const uint2*)(h1b + (size_t)sj1 * 256 + lane * 4);
            uint2 u2 = *(const uint2*)(h1b + (size_t)sj2 * 256 + lane * 4);
            uint2 u3 = *(const uint2*)(h1b + (size_t)sj3 * 256 + lane * 4);
            a0 += wj0.x * bflo(u0.x); a1 += wj0.y * bfhi(u0.x);
            a2 += wj0.z * bflo(u0.y); a3 += wj0.w * bfhi(u0.y);
            a0 += wj1.x * bflo(u1.x); a1 += wj1.y * bfhi(u1.x);
            a2 += wj1.z * bflo(u1.y); a3 += wj1.w * bfhi(u1.y);
            a0 += wj2.x * bflo(u2.x); a1 += wj2.y * bfhi(u2.x);
            a2 += wj2.z * bflo(u2.y); a3 += wj2.w * bfhi(u2.y);
            a0 += wj3.x * bflo(u3.x); a1 += wj3.y * bfhi(u3.x);
            a2 += wj3.z * bflo(u3.y); a3 += wj3.w * bfhi(u3.y);
        }
    }
    // epilogue: normalize + bias + ELU, write x2b bf16, fold layer-2 scores
    float v0 = a0 / l0 + b1[lane];
    float v1 = a1 / l1 + b1[64 + lane];
    float v2 = a2 / l2 + b1[128 + lane];
    float v3 = a3 / l3 + b1[192 + lane];
    v0 = v0 > 0.f ? v0 : __expf(v0) - 1.f;
    v1 = v1 > 0.f ? v1 : __expf(v1) - 1.f;
    v2 = v2 > 0.f ? v2 : __expf(v2) - 1.f;
    v3 = v3 > 0.f ? v3 : __expf(v3) - 1.f;
    ushort_t* xp = x2b + (size_t)d * 256;
    xp[lane] = f2bf(v0); xp[64 + lane] = f2bf(v1);
    xp[128 + lane] = f2bf(v2); xp[192 + lane] = f2bf(v3);
    float sa = v0 * va[lane] + v1 * va[64 + lane] + v2 * va[128 + lane] + v3 * va[192 + lane];
    float sb = v0 * vb[lane] + v1 * vb[64 + lane] + v2 * vb[128 + lane] + v3 * vb[192 + lane];
    sa = wrsum(sa);
    sb = wrsum(sb);
    if (lane == 0) { ssrc2[d] = sa; sdst2[d] = sb; }
}

// ---------- layer-2 feature aggregation (pre-GEMM, via linearity): x2b 512B rows ----------
__global__ __launch_bounds__(256) void aggx_kernel(const int* __restrict__ rowptr,
                                                   const int* __restrict__ srcbuf,
                                                   const float* __restrict__ ssrc,
                                                   const float* __restrict__ sdst,
                                                   const ushort_t* __restrict__ x2b,
                                                   ushort_t* __restrict__ yb, int N) {
    __shared__ int   s_sh[4][64];
    __shared__ float w_sh[4][64];
    int lane = threadIdx.x & 63, w = threadIdx.x >> 6;
    int d = blockIdx.x * 4 + w;
    if (d >= N) return;
    int row = rowptr[d], end = rowptr[d + 1];
    float sdv = sdst[d];
    float m = -INFINITY, l = 0.f;
    float a0 = 0.f, a1 = 0.f, a2 = 0.f, a3 = 0.f;
    for (int base = row; base < end; base += 64) {
        int cnt = min(64, end - base);
        bool valid = lane < cnt;
        int s = valid ? srcbuf[base + lane] : 0;
        float e = lrelu(ssrc[s] + sdv);
        if (!valid) e = -INFINITY;
        float nm = fmaxf(m, wrmax(e));
        float sc = __expf(m - nm);
        float wt = __expf(e - nm);
        l = l * sc + wrsum(wt);
        a0 *= sc; a1 *= sc; a2 *= sc; a3 *= sc;
        m = nm;
        s_sh[w][lane] = s;
        w_sh[w][lane] = wt;
        int cnt4 = (cnt + 3) & ~3;
        for (int j = 0; j < cnt4; j += 4) {
            int sj0 = s_sh[w][j], sj1 = s_sh[w][j + 1], sj2 = s_sh[w][j + 2], sj3 = s_sh[w][j + 3];
            float wj0 = w_sh[w][j], wj1 = w_sh[w][j + 1], wj2 = w_sh[w][j + 2], wj3 = w_sh[w][j + 3];
            uint2 u0 = *(const uint2*)(x2b + (size_t)sj0 * 256 + lane * 4);
            uint2 u1 = *(const uint2*)(x2b + (size_t)sj1 * 256 + lane * 4);
            uint2 u2 = *(const uint2*)(x2b + (size_t)sj2 * 256 + lane * 4);
            uint2 u3 = *(const uint2*)(x2b + (size_t)sj3 * 256 + lane * 4);
            a0 += wj0 * bflo(u0.x); a1 += wj0 * bfhi(u0.x);
            a2 += wj0 * bflo(u0.y); a3 += wj0 * bfhi(u0.y);
            a0 += wj1 * bflo(u1.x); a1 += wj1 * bfhi(u1.x);
            a2 += wj1 * bflo(u1.y); a3 += wj1 * bfhi(u1.y);
            a0 += wj2 * bflo(u2.x); a1 += wj2 * bfhi(u2.x);
            a2 += wj2 * bflo(u2.y); a3 += wj2 * bfhi(u2.y);
            a0 += wj3 * bflo(u3.x); a1 += wj3 * bfhi(u3.x);
            a2 += wj3 * bflo(u3.y); a3 += wj3 * bfhi(u3.y);
        }
    }
    float inv = 1.f / l;
    unsigned p0 = (unsigned)f2bf(a0 * inv) | ((unsigned)f2bf(a1 * inv) << 16);
    unsigned p1 = (unsigned)f2bf(a2 * inv) | ((unsigned)f2bf(a3 * inv) << 16);
    *(uint2*)(yb + (size_t)d * 256 + lane * 4) = make_uint2(p0, p1);
}

// ---------- final GEMM: (y @ W2 + b2), fused global min; y in bf16 ----------
__global__ __launch_bounds__(256) void gemm2min_kernel(const ushort_t* __restrict__ yb,
                                                       const float* __restrict__ W,
                                                       const float* __restrict__ b2,
                                                       unsigned* __restrict__ minenc, int N) {
    __shared__ float xs[16 * 256];
    int base = blockIdx.x * 16;
    int tid = threadIdx.x;
    const uint4* xv = (const uint4*)(yb + (size_t)base * 256);   // 32 uint4 per row
    #pragma unroll
    for (int i = tid; i < 512; i += 256) {
        int n = base + (i >> 5);
        uint4 u = (n < N) ? xv[i] : make_uint4(0u, 0u, 0u, 0u);
        float* dst = xs + i * 8;
        dst[0] = bflo(u.x); dst[1] = bfhi(u.x); dst[2] = bflo(u.y); dst[3] = bfhi(u.y);
        dst[4] = bflo(u.z); dst[5] = bfhi(u.z); dst[6] = bflo(u.w); dst[7] = bfhi(u.w);
    }
    __syncthreads();
    int c = tid & 63, sub = tid >> 6;
    float acc[4] = {0.f, 0.f, 0.f, 0.f};
    for (int k = 0; k < 256; k += 4) {
        float w0 = W[k * 64 + c];
        float w1 = W[(k + 1) * 64 + c];
        float w2 = W[(k + 2) * 64 + c];
        float w3 = W[(k + 3) * 64 + c];
        #pragma unroll
        for (int j = 0; j < 4; j++) {
            float4 xj = *(const float4*)(xs + (sub + 4 * j) * 256 + k);
            acc[j] += xj.x * w0 + xj.y * w1 + xj.z * w2 + xj.w * w3;
        }
    }
    float bc = b2[c];
    float mv = INFINITY;
    #pragma unroll
    for (int j = 0; j < 4; j++) {
        int n = base + sub + 4 * j;
        if (n < N) mv = fminf(mv, acc[j] + bc);
    }
    __shared__ float sm[256];
    sm[tid] = mv;
    __syncthreads();
    if (sub == 0) {
        float v = fminf(fminf(sm[c], sm[64 + c]), fminf(sm[128 + c], sm[192 + c]));
        atomicMin(&minenc[c], fenc(v));
    }
}

__global__ void decode_kernel(const unsigned* __restrict__ minenc, float* __restrict__ out) {
    int d = threadIdx.x;
    if (d < 64) out[d] = fdec(minenc[d]);
}

// ---------- launch ----------
extern "C" void kernel_launch(void* const* d_in, const int* in_sizes, int n_in,
                              void* d_out, int out_size, void* d_ws, size_t ws_size,
                              hipStream_t stream) {
    const float* x      = (const float*)d_in[0];
    const int*   ei     = (const int*)d_in[1];
    const float* W1     = (const float*)d_in[2];
    const float* a_src1 = (const float*)d_in[3];
    const float* a_dst1 = (const float*)d_in[4];
    const float* b1     = (const float*)d_in[5];
    const float* W2     = (const float*)d_in[6];
    const float* a_src2 = (const float*)d_in[7];
    const float* a_dst2 = (const float*)d_in[8];
    const float* b2     = (const float*)d_in[9];
    float* out = (float*)d_out;

    const int N = in_sizes[0] / 128;
    const int E = in_sizes[1] / 2;
    const int Etot = E + N;
    const int Epad = Etot + 64;
    const int M = N + 1;
    const int nchunks = (M + 255) / 256;   // <= 256 for N <= ~65k

    // workspace layout (4-byte words; N divisible by 4 keeps 16B alignment)
    float* ws = (float*)d_ws;
    ushort_t* h1b = (ushort_t*)ws;                     // N*256 bf16 = N*128 words
    ushort_t* x2b = (ushort_t*)(ws + (size_t)N * 128); // N*256 bf16 = N*128 words
    ushort_t* yb  = (ushort_t*)(ws + (size_t)N * 256); // N*256 bf16 = N*128 words
    float* ssrc1  = ws + (size_t)N * 384;              // 4N (16B aligned)
    float* sdst1  = ssrc1 + (size_t)N * 4;             // 4N
    float* ssrc2  = sdst1 + (size_t)N * 4;             // N
    float* sdst2  = ssrc2 + N;                         // N
    float* va     = sdst2 + N;                         // 256
    float* vb     = va + 256;                          // 256
    int*   deg    = (int*)(vb + 256);                  // N+1
    int*   rowptr = deg + M;                           // N+1
    int*   cursor = rowptr + M;                        // N
    int*   csum   = cursor + N;                        // 256
    int*   coff   = csum + 256;                        // 256
    int*   srcbuf = coff + 256;                        // Epad
    unsigned* minenc = (unsigned*)(srcbuf + Epad);     // 64

    hipMemsetAsync(deg, 0, (size_t)M * 4, stream);
    hipMemsetAsync(minenc, 0xFF, 64 * 4, stream);

    int nb16 = (N + 15) / 16;
    int nb4 = (N + 3) / 4;
    gemm1_kernel<<<nb16, 256, 0, stream>>>(x, W1, a_src1, a_dst1, h1b, ssrc1, sdst1, N);

    hist_kernel<<<(Etot + 255) / 256, 256, 0, stream>>>(ei, deg, E, Etot);
    chunksum_kernel<<<nchunks, 256, 0, stream>>>(deg, csum, M);
    scanchunks_kernel<<<1, 256, 0, stream>>>(csum, coff, nchunks);
    rowptr_kernel<<<nchunks, 256, 0, stream>>>(deg, coff, rowptr, cursor, M, N);
    scatter_kernel<<<(Etot + 255) / 256, 256, 0, stream>>>(ei, cursor, srcbuf, E, Etot);

    vab_kernel<<<1, 256, 0, stream>>>(W2, a_src2, a_dst2, va, vb);

    agg1_kernel<<<nb4, 256, 0, stream>>>(rowptr, srcbuf, ssrc1, sdst1, h1b, b1,
                                         va, vb, x2b, ssrc2, sdst2, N);
    aggx_kernel<<<nb4, 256, 0, stream>>>(rowptr, srcbuf, ssrc2, sdst2, x2b, yb, N);
    gemm2min_kernel<<<nb16, 256, 0, stream>>>(yb, W2, b2, minenc, N);
    decode_kernel<<<1, 64, 0, stream>>>(minenc, out);
}

// Round 10
// 418.284 us; speedup vs baseline: 1.2050x; 1.2050x over previous
//
#include <hip/hip_runtime.h>
#include <math.h>

typedef unsigned short ushort_t;
typedef __attribute__((ext_vector_type(8))) short bf16x8;
typedef __attribute__((ext_vector_type(4))) float f32x4;

// ---------- helpers ----------

__device__ inline unsigned fenc(float f) {
    unsigned u = __float_as_uint(f);
    return (u & 0x80000000u) ? ~u : (u | 0x80000000u);
}
__device__ inline float fdec(unsigned u) {
    return __uint_as_float((u & 0x80000000u) ? (u ^ 0x80000000u) : ~u);
}

__device__ inline float wrsum(float v) {
    #pragma unroll
    for (int m = 32; m; m >>= 1) v += __shfl_xor(v, m, 64);
    return v;
}
__device__ inline float wrmax(float v) {
    #pragma unroll
    for (int m = 32; m; m >>= 1) v = fmaxf(v, __shfl_xor(v, m, 64));
    return v;
}
__device__ inline float lrelu(float x) { return x > 0.f ? x : 0.2f * x; }

__device__ inline ushort_t f2bf(float f) {
    unsigned u = __float_as_uint(f);
    u += 0x7FFFu + ((u >> 16) & 1u);      // round-to-nearest-even
    return (ushort_t)(u >> 16);
}
__device__ inline float bflo(unsigned u) { return __uint_as_float(u << 16); }
__device__ inline float bfhi(unsigned u) { return __uint_as_float(u & 0xFFFF0000u); }

// ---------- W1 -> bf16 B-fragment swizzle: W1s[kc][ct][lane][j] ----------
// b_frag element: B[k=kc*32+quad*8+j][n=ct*16+(lane&15)], quad=lane>>4
__global__ __launch_bounds__(256) void wswz_kernel(const float* __restrict__ W1,
                                                   ushort_t* __restrict__ W1s) {
    int idx = blockIdx.x * 256 + threadIdx.x;     // 32768 total
    int j = idx & 7;
    int lane = (idx >> 3) & 63;
    int ct = (idx >> 9) & 15;
    int kc = (idx >> 13) & 3;
    int k = kc * 32 + (lane >> 4) * 8 + j;
    int c = ct * 16 + (lane & 15);
    W1s[idx] = f2bf(W1[k * 256 + c]);
}

// ---------- GEMM 1 via MFMA + fused scores1.  h1b[n][dd][h] permuted bf16 ----------
__global__ __launch_bounds__(256) void gemm1_kernel(const float* __restrict__ x,
                                                    const ushort_t* __restrict__ W1s,
                                                    const float* __restrict__ a_src,
                                                    const float* __restrict__ a_dst,
                                                    ushort_t* __restrict__ h1b,
                                                    float* __restrict__ ssrc,
                                                    float* __restrict__ sdst, int N) {
    __shared__ float ss[16 * 257];      // D-tile transpose: [node j][col c]
    __shared__ float ps[256];           // score partials
    int base = blockIdx.x * 16;
    int tid = threadIdx.x;
    int lane = tid & 63, wv = tid >> 6;
    int m = lane & 15, q = lane >> 4;

    // A-fragments: A[m][k = kc*32 + q*8 + j] from x rows (zero-padded at tail)
    bool rowok = (base + m) < N;
    bf16x8 afrag[4];
    #pragma unroll
    for (int kc = 0; kc < 4; kc++) {
        float4 xa = make_float4(0.f, 0.f, 0.f, 0.f), xb = xa;
        if (rowok) {
            const float* xp = x + (size_t)(base + m) * 128 + kc * 32 + q * 8;
            xa = *(const float4*)xp;
            xb = *(const float4*)(xp + 4);
        }
        bf16x8 af;
        af[0] = (short)f2bf(xa.x); af[1] = (short)f2bf(xa.y);
        af[2] = (short)f2bf(xa.z); af[3] = (short)f2bf(xa.w);
        af[4] = (short)f2bf(xb.x); af[5] = (short)f2bf(xb.y);
        af[6] = (short)f2bf(xb.z); af[7] = (short)f2bf(xb.w);
        afrag[kc] = af;
    }

    // 4 col-tiles per wave, 4 K-chunks each
    #pragma unroll
    for (int t = 0; t < 4; t++) {
        int ct = wv * 4 + t;
        f32x4 acc = {0.f, 0.f, 0.f, 0.f};
        #pragma unroll
        for (int kc = 0; kc < 4; kc++) {
            bf16x8 bfrag = *(const bf16x8*)(W1s + (((size_t)(kc * 16 + ct) * 64 + lane) << 3));
            acc = __builtin_amdgcn_mfma_f32_16x16x32_bf16(afrag[kc], bfrag, acc, 0, 0, 0);
        }
        // D: row = q*4+reg (node j), col = ct*16 + m
        #pragma unroll
        for (int reg = 0; reg < 4; reg++) {
            ss[(q * 4 + reg) * 257 + ct * 16 + m] = acc[reg];
        }
    }
    __syncthreads();

    // ---- h1b stores from ss (thread tid = col) ----
    int dd = tid & 63, hh = tid >> 6;
    #pragma unroll
    for (int j = 0; j < 16; j++) {
        int n = base + j;
        if (n < N) h1b[(size_t)n * 256 + dd * 4 + hh] = f2bf(ss[j * 257 + tid]);
    }
    // ---- scores via partial sums (hh2-rotated) ----
    int j = tid & 15, hh2 = (tid >> 4) & 3, which = (tid >> 6) & 1, half = tid >> 7;
    const float* av = which ? a_dst : a_src;
    int cbase = hh2 * 64 + half * 32;
    float sum = 0.f;
    #pragma unroll
    for (int i = 0; i < 32; i++) {
        int ii = (i + 8 * hh2) & 31;
        sum += ss[j * 257 + cbase + ii] * av[cbase + ii];
    }
    ps[tid] = sum;
    __syncthreads();
    if (half == 0) {
        float tot = sum + ps[tid + 128];
        int n = base + j;
        if (n < N) (which ? sdst : ssrc)[n * 4 + hh2] = tot;
    }
}

// ---------- CSR build ----------
__global__ __launch_bounds__(256) void hist_kernel(const int* __restrict__ ei,
                                                   int* __restrict__ deg, int E, int Etot) {
    int i = blockIdx.x * 256 + threadIdx.x;
    if (i >= Etot) return;
    int d = (i < E) ? ei[E + i] : (i - E);
    atomicAdd(&deg[d], 1);
}

__global__ __launch_bounds__(256) void chunksum_kernel(const int* __restrict__ deg,
                                                       int* __restrict__ csum, int M) {
    __shared__ int sm[256];
    int t = blockIdx.x * 256 + threadIdx.x;
    sm[threadIdx.x] = (t < M) ? deg[t] : 0;
    __syncthreads();
    for (int off = 128; off > 0; off >>= 1) {
        if (threadIdx.x < off) sm[threadIdx.x] += sm[threadIdx.x + off];
        __syncthreads();
    }
    if (threadIdx.x == 0) csum[blockIdx.x] = sm[0];
}

__global__ __launch_bounds__(256) void scanchunks_kernel(const int* __restrict__ csum,
                                                         int* __restrict__ coffset, int nchunks) {
    __shared__ int sm[256];
    int v = (threadIdx.x < nchunks) ? csum[threadIdx.x] : 0;
    sm[threadIdx.x] = v;
    __syncthreads();
    for (int off = 1; off < 256; off <<= 1) {
        int a = (threadIdx.x >= off) ? sm[threadIdx.x - off] : 0;
        __syncthreads();
        sm[threadIdx.x] += a;
        __syncthreads();
    }
    coffset[threadIdx.x] = sm[threadIdx.x] - v;
}

__global__ __launch_bounds__(256) void rowptr_kernel(const int* __restrict__ deg,
                                                     const int* __restrict__ coffset,
                                                     int* __restrict__ rowptr,
                                                     int* __restrict__ cursor, int M, int N) {
    __shared__ int sm[256];
    int t = blockIdx.x * 256 + threadIdx.x;
    int v = (t < M) ? deg[t] : 0;
    sm[threadIdx.x] = v;
    __syncthreads();
    for (int off = 1; off < 256; off <<= 1) {
        int a = (threadIdx.x >= off) ? sm[threadIdx.x - off] : 0;
        __syncthreads();
        sm[threadIdx.x] += a;
        __syncthreads();
    }
    if (t < M) {
        int rp = coffset[blockIdx.x] + sm[threadIdx.x] - v;
        rowptr[t] = rp;
        if (t < N) cursor[t] = rp;
    }
}

__global__ __launch_bounds__(256) void scatter_kernel(const int* __restrict__ ei,
                                                      int* __restrict__ cursor,
                                                      int* __restrict__ srcbuf, int E, int Etot) {
    int i = blockIdx.x * 256 + threadIdx.x;
    if (i >= Etot) return;
    int s, d;
    if (i < E) { s = ei[i]; d = ei[E + i]; } else { s = d = i - E; }
    int pos = atomicAdd(&cursor[d], 1);
    srcbuf[pos] = s;
}

// ---------- va/vb = W2 @ a_src2 / a_dst2 (folded layer-2 score vectors) ----------
__global__ __launch_bounds__(256) void vab_kernel(const float* __restrict__ W2,
                                                  const float* __restrict__ a_src2,
                                                  const float* __restrict__ a_dst2,
                                                  float* __restrict__ va,
                                                  float* __restrict__ vb) {
    int k = threadIdx.x;
    float sa = 0.f, sb = 0.f;
    #pragma unroll 8
    for (int c = 0; c < 64; c++) {
        float w = W2[k * 64 + c];
        sa += w * a_src2[c];
        sb += w * a_dst2[c];
    }
    va[k] = sa;
    vb[k] = sb;
}

// ---------- layer-1 aggregation: bf16 512B rows, inline softmax ----------
__global__ __launch_bounds__(256) void agg1_kernel(const int* __restrict__ rowptr,
                                                   const int* __restrict__ srcbuf,
                                                   const float* __restrict__ ssrc,
                                                   const float* __restrict__ sdst,
                                                   const ushort_t* __restrict__ h1b,
                                                   const float* __restrict__ b1,
                                                   const float* __restrict__ va,
                                                   const float* __restrict__ vb,
                                                   ushort_t* __restrict__ x2b,
                                                   float* __restrict__ ssrc2,
                                                   float* __restrict__ sdst2, int N) {
    __shared__ int    s_sh[4][64];
    __shared__ float4 w_sh[4][64];
    int lane = threadIdx.x & 63, w = threadIdx.x >> 6;
    int d = blockIdx.x * 4 + w;
    if (d >= N) return;
    int row = rowptr[d], end = rowptr[d + 1];
    float4 sd = *(const float4*)(sdst + d * 4);
    float m0 = -INFINITY, m1 = -INFINITY, m2 = -INFINITY, m3 = -INFINITY;
    float l0 = 0.f, l1 = 0.f, l2 = 0.f, l3 = 0.f;
    float a0 = 0.f, a1 = 0.f, a2 = 0.f, a3 = 0.f;

    for (int base = row; base < end; base += 64) {
        int cnt = min(64, end - base);
        bool valid = lane < cnt;
        int s = valid ? srcbuf[base + lane] : 0;
        float4 ssv = *(const float4*)(ssrc + s * 4);
        float e0 = ssv.x + sd.x, e1 = ssv.y + sd.y, e2 = ssv.z + sd.z, e3 = ssv.w + sd.w;
        e0 = lrelu(e0); e1 = lrelu(e1); e2 = lrelu(e2); e3 = lrelu(e3);
        if (!valid) { e0 = e1 = e2 = e3 = -INFINITY; }
        float nm0 = fmaxf(m0, wrmax(e0)), nm1 = fmaxf(m1, wrmax(e1));
        float nm2 = fmaxf(m2, wrmax(e2)), nm3 = fmaxf(m3, wrmax(e3));
        float sc0 = __expf(m0 - nm0), sc1 = __expf(m1 - nm1);
        float sc2 = __expf(m2 - nm2), sc3 = __expf(m3 - nm3);
        float w0 = __expf(e0 - nm0), w1 = __expf(e1 - nm1);
        float w2 = __expf(e2 - nm2), w3 = __expf(e3 - nm3);
        l0 = l0 * sc0 + wrsum(w0);  l1 = l1 * sc1 + wrsum(w1);
        l2 = l2 * sc2 + wrsum(w2);  l3 = l3 * sc3 + wrsum(w3);
        a0 *= sc0; a1 *= sc1; a2 *= sc2; a3 *= sc3;
        m0 = nm0; m1 = nm1; m2 = nm2; m3 = nm3;
        s_sh[w][lane] = s;
        w_sh[w][lane] = make_float4(w0, w1, w2, w3);
        int cnt4 = (cnt + 3) & ~3;
        for (int j = 0; j < cnt4; j += 4) {
            int sj0 = s_sh[w][j], sj1 = s_sh[w][j + 1], sj2 = s_sh[w][j + 2], sj3 = s_sh[w][j + 3];
            float4 wj0 = w_sh[w][j], wj1 = w_sh[w][j + 1], wj2 = w_sh[w][j + 2], wj3 = w_sh[w][j + 3];
            uint2 u0 = *(const uint2*)(h1b + (size_t)sj0 * 256 + lane * 4);
            uint2 u1 = *(const uint2*)(h1b + (size_t)sj1 * 256 + lane * 4);
            uint2 u2 = *(const uint2*)(h1b + (size_t)sj2 * 256 + lane * 4);
            uint2 u3 = *(const uint2*)(h1b + (size_t)sj3 * 256 + lane * 4);
            a0 += wj0.x * bflo(u0.x); a1 += wj0.y * bfhi(u0.x);
            a2 += wj0.z * bflo(u0.y); a3 += wj0.w * bfhi(u0.y);
            a0 += wj1.x * bflo(u1.x); a1 += wj1.y * bfhi(u1.x);
            a2 += wj1.z * bflo(u1.y); a3 += wj1.w * bfhi(u1.y);
            a0 += wj2.x * bflo(u2.x); a1 += wj2.y * bfhi(u2.x);
            a2 += wj2.z * bflo(u2.y); a3 += wj2.w * bfhi(u2.y);
            a0 += wj3.x * bflo(u3.x); a1 += wj3.y * bfhi(u3.x);
            a2 += wj3.z * bflo(u3.y); a3 += wj3.w * bfhi(u3.y);
        }
    }
    float v0 = a0 / l0 + b1[lane];
    float v1 = a1 / l1 + b1[64 + lane];
    float v2 = a2 / l2 + b1[128 + lane];
    float v3 = a3 / l3 + b1[192 + lane];
    v0 = v0 > 0.f ? v0 : __expf(v0) - 1.f;
    v1 = v1 > 0.f ? v1 : __expf(v1) - 1.f;
    v2 = v2 > 0.f ? v2 : __expf(v2) - 1.f;
    v3 = v3 > 0.f ? v3 : __expf(v3) - 1.f;
    ushort_t* xp = x2b + (size_t)d * 256;
    xp[lane] = f2bf(v0); xp[64 + lane] = f2bf(v1);
    xp[128 + lane] = f2bf(v2); xp[192 + lane] = f2bf(v3);
    float sa = v0 * va[lane] + v1 * va[64 + lane] + v2 * va[128 + lane] + v3 * va[192 + lane];
    float sb = v0 * vb[lane] + v1 * vb[64 + lane] + v2 * vb[128 + lane] + v3 * vb[192 + lane];
    sa = wrsum(sa);
    sb = wrsum(sb);
    if (lane == 0) { ssrc2[d] = sa; sdst2[d] = sb; }
}

// ---------- layer-2 feature aggregation (pre-GEMM, via linearity) ----------
__global__ __launch_bounds__(256) void aggx_kernel(const int* __restrict__ rowptr,
                                                   const int* __restrict__ srcbuf,
                                                   const float* __restrict__ ssrc,
                                                   const float* __restrict__ sdst,
                                                   const ushort_t* __restrict__ x2b,
                                                   ushort_t* __restrict__ yb, int N) {
    __shared__ int   s_sh[4][64];
    __shared__ float w_sh[4][64];
    int lane = threadIdx.x & 63, w = threadIdx.x >> 6;
    int d = blockIdx.x * 4 + w;
    if (d >= N) return;
    int row = rowptr[d], end = rowptr[d + 1];
    float sdv = sdst[d];
    float m = -INFINITY, l = 0.f;
    float a0 = 0.f, a1 = 0.f, a2 = 0.f, a3 = 0.f;
    for (int base = row; base < end; base += 64) {
        int cnt = min(64, end - base);
        bool valid = lane < cnt;
        int s = valid ? srcbuf[base + lane] : 0;
        float e = lrelu(ssrc[s] + sdv);
        if (!valid) e = -INFINITY;
        float nm = fmaxf(m, wrmax(e));
        float sc = __expf(m - nm);
        float wt = __expf(e - nm);
        l = l * sc + wrsum(wt);
        a0 *= sc; a1 *= sc; a2 *= sc; a3 *= sc;
        m = nm;
        s_sh[w][lane] = s;
        w_sh[w][lane] = wt;
        int cnt4 = (cnt + 3) & ~3;
        for (int j = 0; j < cnt4; j += 4) {
            int sj0 = s_sh[w][j], sj1 = s_sh[w][j + 1], sj2 = s_sh[w][j + 2], sj3 = s_sh[w][j + 3];
            float wj0 = w_sh[w][j], wj1 = w_sh[w][j + 1], wj2 = w_sh[w][j + 2], wj3 = w_sh[w][j + 3];
            uint2 u0 = *(const uint2*)(x2b + (size_t)sj0 * 256 + lane * 4);
            uint2 u1 = *(const uint2*)(x2b + (size_t)sj1 * 256 + lane * 4);
            uint2 u2 = *(const uint2*)(x2b + (size_t)sj2 * 256 + lane * 4);
            uint2 u3 = *(const uint2*)(x2b + (size_t)sj3 * 256 + lane * 4);
            a0 += wj0 * bflo(u0.x); a1 += wj0 * bfhi(u0.x);
            a2 += wj0 * bflo(u0.y); a3 += wj0 * bfhi(u0.y);
            a0 += wj1 * bflo(u1.x); a1 += wj1 * bfhi(u1.x);
            a2 += wj1 * bflo(u1.y); a3 += wj1 * bfhi(u1.y);
            a0 += wj2 * bflo(u2.x); a1 += wj2 * bfhi(u2.x);
            a2 += wj2 * bflo(u2.y); a3 += wj2 * bfhi(u2.y);
            a0 += wj3 * bflo(u3.x); a1 += wj3 * bfhi(u3.x);
            a2 += wj3 * bflo(u3.y); a3 += wj3 * bfhi(u3.y);
        }
    }
    float inv = 1.f / l;
    unsigned p0 = (unsigned)f2bf(a0 * inv) | ((unsigned)f2bf(a1 * inv) << 16);
    unsigned p1 = (unsigned)f2bf(a2 * inv) | ((unsigned)f2bf(a3 * inv) << 16);
    *(uint2*)(yb + (size_t)d * 256 + lane * 4) = make_uint2(p0, p1);
}

// ---------- final GEMM: (y @ W2 + b2), fused global min; y in bf16 ----------
__global__ __launch_bounds__(256) void gemm2min_kernel(const ushort_t* __restrict__ yb,
                                                       const float* __restrict__ W,
                                                       const float* __restrict__ b2,
                                                       unsigned* __restrict__ minenc, int N) {
    __shared__ float xs[16 * 256];
    int base = blockIdx.x * 16;
    int tid = threadIdx.x;
    const uint4* xv = (const uint4*)(yb + (size_t)base * 256);
    #pragma unroll
    for (int i = tid; i < 512; i += 256) {
        int n = base + (i >> 5);
        uint4 u = (n < N) ? xv[i] : make_uint4(0u, 0u, 0u, 0u);
        float* dst = xs + i * 8;
        dst[0] = bflo(u.x); dst[1] = bfhi(u.x); dst[2] = bflo(u.y); dst[3] = bfhi(u.y);
        dst[4] = bflo(u.z); dst[5] = bfhi(u.z); dst[6] = bflo(u.w); dst[7] = bfhi(u.w);
    }
    __syncthreads();
    int c = tid & 63, sub = tid >> 6;
    float acc[4] = {0.f, 0.f, 0.f, 0.f};
    for (int k = 0; k < 256; k += 4) {
        float w0 = W[k * 64 + c];
        float w1 = W[(k + 1) * 64 + c];
        float w2 = W[(k + 2) * 64 + c];
        float w3 = W[(k + 3) * 64 + c];
        #pragma unroll
        for (int j = 0; j < 4; j++) {
            float4 xj = *(const float4*)(xs + (sub + 4 * j) * 256 + k);
            acc[j] += xj.x * w0 + xj.y * w1 + xj.z * w2 + xj.w * w3;
        }
    }
    float bc = b2[c];
    float mv = INFINITY;
    #pragma unroll
    for (int j = 0; j < 4; j++) {
        int n = base + sub + 4 * j;
        if (n < N) mv = fminf(mv, acc[j] + bc);
    }
    __shared__ float sm[256];
    sm[tid] = mv;
    __syncthreads();
    if (sub == 0) {
        float v = fminf(fminf(sm[c], sm[64 + c]), fminf(sm[128 + c], sm[192 + c]));
        atomicMin(&minenc[c], fenc(v));
    }
}

__global__ void decode_kernel(const unsigned* __restrict__ minenc, float* __restrict__ out) {
    int d = threadIdx.x;
    if (d < 64) out[d] = fdec(minenc[d]);
}

// ---------- launch ----------
extern "C" void kernel_launch(void* const* d_in, const int* in_sizes, int n_in,
                              void* d_out, int out_size, void* d_ws, size_t ws_size,
                              hipStream_t stream) {
    const float* x      = (const float*)d_in[0];
    const int*   ei     = (const int*)d_in[1];
    const float* W1     = (const float*)d_in[2];
    const float* a_src1 = (const float*)d_in[3];
    const float* a_dst1 = (const float*)d_in[4];
    const float* b1     = (const float*)d_in[5];
    const float* W2     = (const float*)d_in[6];
    const float* a_src2 = (const float*)d_in[7];
    const float* a_dst2 = (const float*)d_in[8];
    const float* b2     = (const float*)d_in[9];
    float* out = (float*)d_out;

    const int N = in_sizes[0] / 128;
    const int E = in_sizes[1] / 2;
    const int Etot = E + N;
    const int Epad = Etot + 64;
    const int M = N + 1;
    const int nchunks = (M + 255) / 256;   // <= 256 for N <= ~65k

    // workspace layout (4-byte words; N divisible by 4 keeps 16B alignment)
    float* ws = (float*)d_ws;
    ushort_t* h1b = (ushort_t*)ws;                     // N*256 bf16 = N*128 words
    ushort_t* x2b = (ushort_t*)(ws + (size_t)N * 128); // N*256 bf16
    ushort_t* yb  = (ushort_t*)(ws + (size_t)N * 256); // N*256 bf16
    ushort_t* W1s = (ushort_t*)(ws + (size_t)N * 384); // 32768 bf16 = 16384 words
    float* ssrc1  = ws + (size_t)N * 384 + 16384;      // 4N (16B aligned)
    float* sdst1  = ssrc1 + (size_t)N * 4;             // 4N
    float* ssrc2  = sdst1 + (size_t)N * 4;             // N
    float* sdst2  = ssrc2 + N;                         // N
    float* va     = sdst2 + N;                         // 256
    float* vb     = va + 256;                          // 256
    int*   deg    = (int*)(vb + 256);                  // N+1
    int*   rowptr = deg + M;                           // N+1
    int*   cursor = rowptr + M;                        // N
    int*   csum   = cursor + N;                        // 256
    int*   coff   = csum + 256;                        // 256
    int*   srcbuf = coff + 256;                        // Epad
    unsigned* minenc = (unsigned*)(srcbuf + Epad);     // 64

    hipMemsetAsync(deg, 0, (size_t)M * 4, stream);
    hipMemsetAsync(minenc, 0xFF, 64 * 4, stream);

    int nb16 = (N + 15) / 16;
    int nb4 = (N + 3) / 4;

    wswz_kernel<<<128, 256, 0, stream>>>(W1, W1s);
    gemm1_kernel<<<nb16, 256, 0, stream>>>(x, W1s, a_src1, a_dst1, h1b, ssrc1, sdst1, N);

    hist_kernel<<<(Etot + 255) / 256, 256, 0, stream>>>(ei, deg, E, Etot);
    chunksum_kernel<<<nchunks, 256, 0, stream>>>(deg, csum, M);
    scanchunks_kernel<<<1, 256, 0, stream>>>(csum, coff, nchunks);
    rowptr_kernel<<<nchunks, 256, 0, stream>>>(deg, coff, rowptr, cursor, M, N);
    scatter_kernel<<<(Etot + 255) / 256, 256, 0, stream>>>(ei, cursor, srcbuf, E, Etot);

    vab_kernel<<<1, 256, 0, stream>>>(W2, a_src2, a_dst2, va, vb);

    agg1_kernel<<<nb4, 256, 0, stream>>>(rowptr, srcbuf, ssrc1, sdst1, h1b, b1,
                                         va, vb, x2b, ssrc2, sdst2, N);
    aggx_kernel<<<nb4, 256, 0, stream>>>(rowptr, srcbuf, ssrc2, sdst2, x2b, yb, N);
    gemm2min_kernel<<<nb16, 256, 0, stream>>>(yb, W2, b2, minenc, N);
    decode_kernel<<<1, 64, 0, stream>>>(minenc, out);
}

// Round 11
// 403.072 us; speedup vs baseline: 1.2505x; 1.0377x over previous
//
#include <hip/hip_runtime.h>
#include <math.h>

typedef unsigned short ushort_t;
typedef __attribute__((ext_vector_type(8))) short bf16x8;
typedef __attribute__((ext_vector_type(4))) float f32x4;

// ---------- helpers ----------

__device__ inline unsigned fenc(float f) {
    unsigned u = __float_as_uint(f);
    return (u & 0x80000000u) ? ~u : (u | 0x80000000u);
}
__device__ inline float fdec(unsigned u) {
    return __uint_as_float((u & 0x80000000u) ? (u ^ 0x80000000u) : ~u);
}

__device__ inline float wrsum(float v) {
    #pragma unroll
    for (int m = 32; m; m >>= 1) v += __shfl_xor(v, m, 64);
    return v;
}
__device__ inline float wrmax(float v) {
    #pragma unroll
    for (int m = 32; m; m >>= 1) v = fmaxf(v, __shfl_xor(v, m, 64));
    return v;
}
__device__ inline float lrelu(float x) { return x > 0.f ? x : 0.2f * x; }

__device__ inline ushort_t f2bf(float f) {
    unsigned u = __float_as_uint(f);
    u += 0x7FFFu + ((u >> 16) & 1u);      // round-to-nearest-even
    return (ushort_t)(u >> 16);
}
__device__ inline float bflo(unsigned u) { return __uint_as_float(u << 16); }
__device__ inline float bfhi(unsigned u) { return __uint_as_float(u & 0xFFFF0000u); }

// ---------- pre kernel: W1/W2 bf16 B-fragment swizzles + vab fold ----------
// W1s: kc(4) x ct(16) x lane(64) x j(8):  B[k=kc*32+q*8+j][c=ct*16+m]
// W2s: kc(8) x ct(4)  x lane(64) x j(8):  B[k=kc*32+q*8+j][c=ct*16+m]
__global__ __launch_bounds__(256) void pre_kernel(const float* __restrict__ W1,
                                                  const float* __restrict__ W2,
                                                  const float* __restrict__ a_src2,
                                                  const float* __restrict__ a_dst2,
                                                  ushort_t* __restrict__ W1s,
                                                  ushort_t* __restrict__ W2s,
                                                  float* __restrict__ va,
                                                  float* __restrict__ vb) {
    int bid = blockIdx.x;
    int tid = threadIdx.x;
    if (bid < 128) {                       // W1 swizzle: 32768 elems
        int idx = bid * 256 + tid;
        int j = idx & 7;
        int lane = (idx >> 3) & 63;
        int ct = (idx >> 9) & 15;
        int kc = (idx >> 13) & 3;
        int k = kc * 32 + (lane >> 4) * 8 + j;
        int c = ct * 16 + (lane & 15);
        W1s[idx] = f2bf(W1[k * 256 + c]);
    } else if (bid < 192) {                // W2 swizzle: 16384 elems
        int idx = (bid - 128) * 256 + tid;
        int j = idx & 7;
        int lane = (idx >> 3) & 63;
        int ct = (idx >> 9) & 3;
        int kc = idx >> 11;
        int k = kc * 32 + (lane >> 4) * 8 + j;
        int c = ct * 16 + (lane & 15);
        W2s[idx] = f2bf(W2[k * 64 + c]);
    } else {                               // vab: va/vb = W2 @ a_src2/a_dst2
        int k = tid;
        float sa = 0.f, sb = 0.f;
        #pragma unroll 8
        for (int c = 0; c < 64; c++) {
            float w = W2[k * 64 + c];
            sa += w * a_src2[c];
            sb += w * a_dst2[c];
        }
        va[k] = sa;
        vb[k] = sb;
    }
}

// ---------- front kernel: MFMA gemm1 (+scores1) merged with hist ----------
__global__ __launch_bounds__(256) void front_kernel(const float* __restrict__ x,
                                                    const ushort_t* __restrict__ W1s,
                                                    const float* __restrict__ a_src,
                                                    const float* __restrict__ a_dst,
                                                    ushort_t* __restrict__ h1b,
                                                    float* __restrict__ ssrc,
                                                    float* __restrict__ sdst,
                                                    const int* __restrict__ ei,
                                                    int* __restrict__ deg,
                                                    int N, int E, int Etot, int nb16) {
    __shared__ float ss[16 * 257];
    __shared__ float ps[256];
    int bid = blockIdx.x;
    int tid = threadIdx.x;

    if (bid >= nb16) {                     // ---- hist part ----
        int i = (bid - nb16) * 256 + tid;
        if (i < Etot) {
            int d = (i < E) ? ei[E + i] : (i - E);
            atomicAdd(&deg[d], 1);
        }
        return;
    }

    // ---- gemm1 via MFMA ----
    int base = bid * 16;
    int lane = tid & 63, wv = tid >> 6;
    int m = lane & 15, q = lane >> 4;

    bool rowok = (base + m) < N;
    bf16x8 afrag[4];
    #pragma unroll
    for (int kc = 0; kc < 4; kc++) {
        float4 xa = make_float4(0.f, 0.f, 0.f, 0.f), xb = xa;
        if (rowok) {
            const float* xp = x + (size_t)(base + m) * 128 + kc * 32 + q * 8;
            xa = *(const float4*)xp;
            xb = *(const float4*)(xp + 4);
        }
        bf16x8 af;
        af[0] = (short)f2bf(xa.x); af[1] = (short)f2bf(xa.y);
        af[2] = (short)f2bf(xa.z); af[3] = (short)f2bf(xa.w);
        af[4] = (short)f2bf(xb.x); af[5] = (short)f2bf(xb.y);
        af[6] = (short)f2bf(xb.z); af[7] = (short)f2bf(xb.w);
        afrag[kc] = af;
    }

    #pragma unroll
    for (int t = 0; t < 4; t++) {
        int ct = wv * 4 + t;
        f32x4 acc = {0.f, 0.f, 0.f, 0.f};
        #pragma unroll
        for (int kc = 0; kc < 4; kc++) {
            bf16x8 bfrag = *(const bf16x8*)(W1s + (((size_t)(kc * 16 + ct) * 64 + lane) << 3));
            acc = __builtin_amdgcn_mfma_f32_16x16x32_bf16(afrag[kc], bfrag, acc, 0, 0, 0);
        }
        #pragma unroll
        for (int reg = 0; reg < 4; reg++) {
            ss[(q * 4 + reg) * 257 + ct * 16 + m] = acc[reg];
        }
    }
    __syncthreads();

    int dd = tid & 63, hh = tid >> 6;
    #pragma unroll
    for (int j = 0; j < 16; j++) {
        int n = base + j;
        if (n < N) h1b[(size_t)n * 256 + dd * 4 + hh] = f2bf(ss[j * 257 + tid]);
    }
    int j = tid & 15, hh2 = (tid >> 4) & 3, which = (tid >> 6) & 1, half = tid >> 7;
    const float* av = which ? a_dst : a_src;
    int cbase = hh2 * 64 + half * 32;
    float sum = 0.f;
    #pragma unroll
    for (int i = 0; i < 32; i++) {
        int ii = (i + 8 * hh2) & 31;
        sum += ss[j * 257 + cbase + ii] * av[cbase + ii];
    }
    ps[tid] = sum;
    __syncthreads();
    if (half == 0) {
        float tot = sum + ps[tid + 128];
        int n = base + j;
        if (n < N) (which ? sdst : ssrc)[n * 4 + hh2] = tot;
    }
}

// ---------- CSR scan chain ----------
__global__ __launch_bounds__(256) void chunksum_kernel(const int* __restrict__ deg,
                                                       int* __restrict__ csum, int M) {
    __shared__ int sm[256];
    int t = blockIdx.x * 256 + threadIdx.x;
    sm[threadIdx.x] = (t < M) ? deg[t] : 0;
    __syncthreads();
    for (int off = 128; off > 0; off >>= 1) {
        if (threadIdx.x < off) sm[threadIdx.x] += sm[threadIdx.x + off];
        __syncthreads();
    }
    if (threadIdx.x == 0) csum[blockIdx.x] = sm[0];
}

__global__ __launch_bounds__(256) void scanchunks_kernel(const int* __restrict__ csum,
                                                         int* __restrict__ coffset, int nchunks) {
    __shared__ int sm[256];
    int v = (threadIdx.x < nchunks) ? csum[threadIdx.x] : 0;
    sm[threadIdx.x] = v;
    __syncthreads();
    for (int off = 1; off < 256; off <<= 1) {
        int a = (threadIdx.x >= off) ? sm[threadIdx.x - off] : 0;
        __syncthreads();
        sm[threadIdx.x] += a;
        __syncthreads();
    }
    coffset[threadIdx.x] = sm[threadIdx.x] - v;
}

__global__ __launch_bounds__(256) void rowptr_kernel(const int* __restrict__ deg,
                                                     const int* __restrict__ coffset,
                                                     int* __restrict__ rowptr,
                                                     int* __restrict__ cursor, int M, int N) {
    __shared__ int sm[256];
    int t = blockIdx.x * 256 + threadIdx.x;
    int v = (t < M) ? deg[t] : 0;
    sm[threadIdx.x] = v;
    __syncthreads();
    for (int off = 1; off < 256; off <<= 1) {
        int a = (threadIdx.x >= off) ? sm[threadIdx.x - off] : 0;
        __syncthreads();
        sm[threadIdx.x] += a;
        __syncthreads();
    }
    if (t < M) {
        int rp = coffset[blockIdx.x] + sm[threadIdx.x] - v;
        rowptr[t] = rp;
        if (t < N) cursor[t] = rp;
    }
}

__global__ __launch_bounds__(256) void scatter_kernel(const int* __restrict__ ei,
                                                      int* __restrict__ cursor,
                                                      int* __restrict__ srcbuf, int E, int Etot) {
    int i = blockIdx.x * 256 + threadIdx.x;
    if (i >= Etot) return;
    int s, d;
    if (i < E) { s = ei[i]; d = ei[E + i]; } else { s = d = i - E; }
    int pos = atomicAdd(&cursor[d], 1);
    srcbuf[pos] = s;
}

// ---------- layer-1 aggregation: bf16 512B rows, inline softmax ----------
__global__ __launch_bounds__(256) void agg1_kernel(const int* __restrict__ rowptr,
                                                   const int* __restrict__ srcbuf,
                                                   const float* __restrict__ ssrc,
                                                   const float* __restrict__ sdst,
                                                   const ushort_t* __restrict__ h1b,
                                                   const float* __restrict__ b1,
                                                   const float* __restrict__ va,
                                                   const float* __restrict__ vb,
                                                   ushort_t* __restrict__ x2b,
                                                   float* __restrict__ ssrc2,
                                                   float* __restrict__ sdst2, int N) {
    __shared__ int    s_sh[4][64];
    __shared__ float4 w_sh[4][64];
    int lane = threadIdx.x & 63, w = threadIdx.x >> 6;
    int d = blockIdx.x * 4 + w;
    if (d >= N) return;
    int row = rowptr[d], end = rowptr[d + 1];
    float4 sd = *(const float4*)(sdst + d * 4);
    float m0 = -INFINITY, m1 = -INFINITY, m2 = -INFINITY, m3 = -INFINITY;
    float l0 = 0.f, l1 = 0.f, l2 = 0.f, l3 = 0.f;
    float a0 = 0.f, a1 = 0.f, a2 = 0.f, a3 = 0.f;

    for (int base = row; base < end; base += 64) {
        int cnt = min(64, end - base);
        bool valid = lane < cnt;
        int s = valid ? srcbuf[base + lane] : 0;
        float4 ssv = *(const float4*)(ssrc + s * 4);
        float e0 = ssv.x + sd.x, e1 = ssv.y + sd.y, e2 = ssv.z + sd.z, e3 = ssv.w + sd.w;
        e0 = lrelu(e0); e1 = lrelu(e1); e2 = lrelu(e2); e3 = lrelu(e3);
        if (!valid) { e0 = e1 = e2 = e3 = -INFINITY; }
        float nm0 = fmaxf(m0, wrmax(e0)), nm1 = fmaxf(m1, wrmax(e1));
        float nm2 = fmaxf(m2, wrmax(e2)), nm3 = fmaxf(m3, wrmax(e3));
        float sc0 = __expf(m0 - nm0), sc1 = __expf(m1 - nm1);
        float sc2 = __expf(m2 - nm2), sc3 = __expf(m3 - nm3);
        float w0 = __expf(e0 - nm0), w1 = __expf(e1 - nm1);
        float w2 = __expf(e2 - nm2), w3 = __expf(e3 - nm3);
        l0 = l0 * sc0 + wrsum(w0);  l1 = l1 * sc1 + wrsum(w1);
        l2 = l2 * sc2 + wrsum(w2);  l3 = l3 * sc3 + wrsum(w3);
        a0 *= sc0; a1 *= sc1; a2 *= sc2; a3 *= sc3;
        m0 = nm0; m1 = nm1; m2 = nm2; m3 = nm3;
        s_sh[w][lane] = s;
        w_sh[w][lane] = make_float4(w0, w1, w2, w3);
        int cnt4 = (cnt + 3) & ~3;
        for (int j = 0; j < cnt4; j += 4) {
            int sj0 = s_sh[w][j], sj1 = s_sh[w][j + 1], sj2 = s_sh[w][j + 2], sj3 = s_sh[w][j + 3];
            float4 wj0 = w_sh[w][j], wj1 = w_sh[w][j + 1], wj2 = w_sh[w][j + 2], wj3 = w_sh[w][j + 3];
            uint2 u0 = *(const uint2*)(h1b + (size_t)sj0 * 256 + lane * 4);
            uint2 u1 = *(const uint2*)(h1b + (size_t)sj1 * 256 + lane * 4);
            uint2 u2 = *(const uint2*)(h1b + (size_t)sj2 * 256 + lane * 4);
            uint2 u3 = *(const uint2*)(h1b + (size_t)sj3 * 256 + lane * 4);
            a0 += wj0.x * bflo(u0.x); a1 += wj0.y * bfhi(u0.x);
            a2 += wj0.z * bflo(u0.y); a3 += wj0.w * bfhi(u0.y);
            a0 += wj1.x * bflo(u1.x); a1 += wj1.y * bfhi(u1.x);
            a2 += wj1.z * bflo(u1.y); a3 += wj1.w * bfhi(u1.y);
            a0 += wj2.x * bflo(u2.x); a1 += wj2.y * bfhi(u2.x);
            a2 += wj2.z * bflo(u2.y); a3 += wj2.w * bfhi(u2.y);
            a0 += wj3.x * bflo(u3.x); a1 += wj3.y * bfhi(u3.x);
            a2 += wj3.z * bflo(u3.y); a3 += wj3.w * bfhi(u3.y);
        }
    }
    float v0 = a0 / l0 + b1[lane];
    float v1 = a1 / l1 + b1[64 + lane];
    float v2 = a2 / l2 + b1[128 + lane];
    float v3 = a3 / l3 + b1[192 + lane];
    v0 = v0 > 0.f ? v0 : __expf(v0) - 1.f;
    v1 = v1 > 0.f ? v1 : __expf(v1) - 1.f;
    v2 = v2 > 0.f ? v2 : __expf(v2) - 1.f;
    v3 = v3 > 0.f ? v3 : __expf(v3) - 1.f;
    ushort_t* xp = x2b + (size_t)d * 256;
    xp[lane] = f2bf(v0); xp[64 + lane] = f2bf(v1);
    xp[128 + lane] = f2bf(v2); xp[192 + lane] = f2bf(v3);
    float sa = v0 * va[lane] + v1 * va[64 + lane] + v2 * va[128 + lane] + v3 * va[192 + lane];
    float sb = v0 * vb[lane] + v1 * vb[64 + lane] + v2 * vb[128 + lane] + v3 * vb[192 + lane];
    sa = wrsum(sa);
    sb = wrsum(sb);
    if (lane == 0) { ssrc2[d] = sa; sdst2[d] = sb; }
}

// ---------- layer-2 feature aggregation (pre-GEMM, via linearity) ----------
__global__ __launch_bounds__(256) void aggx_kernel(const int* __restrict__ rowptr,
                                                   const int* __restrict__ srcbuf,
                                                   const float* __restrict__ ssrc,
                                                   const float* __restrict__ sdst,
                                                   const ushort_t* __restrict__ x2b,
                                                   ushort_t* __restrict__ yb, int N) {
    __shared__ int   s_sh[4][64];
    __shared__ float w_sh[4][64];
    int lane = threadIdx.x & 63, w = threadIdx.x >> 6;
    int d = blockIdx.x * 4 + w;
    if (d >= N) return;
    int row = rowptr[d], end = rowptr[d + 1];
    float sdv = sdst[d];
    float m = -INFINITY, l = 0.f;
    float a0 = 0.f, a1 = 0.f, a2 = 0.f, a3 = 0.f;
    for (int base = row; base < end; base += 64) {
        int cnt = min(64, end - base);
        bool valid = lane < cnt;
        int s = valid ? srcbuf[base + lane] : 0;
        float e = lrelu(ssrc[s] + sdv);
        if (!valid) e = -INFINITY;
        float nm = fmaxf(m, wrmax(e));
        float sc = __expf(m - nm);
        float wt = __expf(e - nm);
        l = l * sc + wrsum(wt);
        a0 *= sc; a1 *= sc; a2 *= sc; a3 *= sc;
        m = nm;
        s_sh[w][lane] = s;
        w_sh[w][lane] = wt;
        int cnt4 = (cnt + 3) & ~3;
        for (int j = 0; j < cnt4; j += 4) {
            int sj0 = s_sh[w][j], sj1 = s_sh[w][j + 1], sj2 = s_sh[w][j + 2], sj3 = s_sh[w][j + 3];
            float wj0 = w_sh[w][j], wj1 = w_sh[w][j + 1], wj2 = w_sh[w][j + 2], wj3 = w_sh[w][j + 3];
            uint2 u0 = *(const uint2*)(x2b + (size_t)sj0 * 256 + lane * 4);
            uint2 u1 = *(const uint2*)(x2b + (size_t)sj1 * 256 + lane * 4);
            uint2 u2 = *(const uint2*)(x2b + (size_t)sj2 * 256 + lane * 4);
            uint2 u3 = *(const uint2*)(x2b + (size_t)sj3 * 256 + lane * 4);
            a0 += wj0 * bflo(u0.x); a1 += wj0 * bfhi(u0.x);
            a2 += wj0 * bflo(u0.y); a3 += wj0 * bfhi(u0.y);
            a0 += wj1 * bflo(u1.x); a1 += wj1 * bfhi(u1.x);
            a2 += wj1 * bflo(u1.y); a3 += wj1 * bfhi(u1.y);
            a0 += wj2 * bflo(u2.x); a1 += wj2 * bfhi(u2.x);
            a2 += wj2 * bflo(u2.y); a3 += wj2 * bfhi(u2.y);
            a0 += wj3 * bflo(u3.x); a1 += wj3 * bfhi(u3.x);
            a2 += wj3 * bflo(u3.y); a3 += wj3 * bfhi(u3.y);
        }
    }
    float inv = 1.f / l;
    unsigned p0 = (unsigned)f2bf(a0 * inv) | ((unsigned)f2bf(a1 * inv) << 16);
    unsigned p1 = (unsigned)f2bf(a2 * inv) | ((unsigned)f2bf(a3 * inv) << 16);
    *(uint2*)(yb + (size_t)d * 256 + lane * 4) = make_uint2(p0, p1);
}

// ---------- final GEMM via MFMA: (y @ W2 + b2), fused global min; 32 nodes/block ----------
__global__ __launch_bounds__(256) void gemm2min_kernel(const ushort_t* __restrict__ yb,
                                                       const ushort_t* __restrict__ W2s,
                                                       const float* __restrict__ b2,
                                                       unsigned* __restrict__ minenc, int N) {
    int base = blockIdx.x * 32;
    int tid = threadIdx.x;
    int lane = tid & 63, wv = tid >> 6;
    int m = lane & 15, q = lane >> 4;
    int c = wv * 16 + m;
    float bc = b2[c];
    float mv = INFINITY;

    #pragma unroll
    for (int h = 0; h < 2; h++) {
        int rbase = base + h * 16;
        bool rowok = (rbase + m) < N;
        const ushort_t* yrow = yb + (size_t)(rbase + m) * 256;
        f32x4 acc = {0.f, 0.f, 0.f, 0.f};
        #pragma unroll
        for (int kc = 0; kc < 8; kc++) {
            bf16x8 af = {0, 0, 0, 0, 0, 0, 0, 0};
            if (rowok) af = *(const bf16x8*)(yrow + kc * 32 + q * 8);
            bf16x8 bf = *(const bf16x8*)(W2s + (((size_t)(kc * 4 + wv) * 64 + lane) << 3));
            acc = __builtin_amdgcn_mfma_f32_16x16x32_bf16(af, bf, acc, 0, 0, 0);
        }
        #pragma unroll
        for (int reg = 0; reg < 4; reg++) {
            int n = rbase + q * 4 + reg;
            if (n < N) mv = fminf(mv, acc[reg] + bc);
        }
    }
    mv = fminf(mv, __shfl_xor(mv, 16, 64));
    mv = fminf(mv, __shfl_xor(mv, 32, 64));
    if (q == 0) atomicMin(&minenc[c], fenc(mv));
}

__global__ void decode_kernel(const unsigned* __restrict__ minenc, float* __restrict__ out) {
    int d = threadIdx.x;
    if (d < 64) out[d] = fdec(minenc[d]);
}

// ---------- launch ----------
extern "C" void kernel_launch(void* const* d_in, const int* in_sizes, int n_in,
                              void* d_out, int out_size, void* d_ws, size_t ws_size,
                              hipStream_t stream) {
    const float* x      = (const float*)d_in[0];
    const int*   ei     = (const int*)d_in[1];
    const float* W1     = (const float*)d_in[2];
    const float* a_src1 = (const float*)d_in[3];
    const float* a_dst1 = (const float*)d_in[4];
    const float* b1     = (const float*)d_in[5];
    const float* W2     = (const float*)d_in[6];
    const float* a_src2 = (const float*)d_in[7];
    const float* a_dst2 = (const float*)d_in[8];
    const float* b2     = (const float*)d_in[9];
    float* out = (float*)d_out;

    const int N = in_sizes[0] / 128;
    const int E = in_sizes[1] / 2;
    const int Etot = E + N;
    const int Epad = Etot + 64;
    const int M = N + 1;
    const int nchunks = (M + 255) / 256;   // <= 256 for N <= ~65k

    // workspace layout (4-byte words; N divisible by 4 keeps 16B alignment)
    float* ws = (float*)d_ws;
    ushort_t* h1b = (ushort_t*)ws;                     // N*256 bf16 = N*128 words
    ushort_t* x2b = (ushort_t*)(ws + (size_t)N * 128); // N*256 bf16
    ushort_t* yb  = (ushort_t*)(ws + (size_t)N * 256); // N*256 bf16
    ushort_t* W1s = (ushort_t*)(ws + (size_t)N * 384); // 32768 bf16 = 16384 words
    ushort_t* W2s = (ushort_t*)(ws + (size_t)N * 384 + 16384); // 16384 bf16 = 8192 words
    float* ssrc1  = ws + (size_t)N * 384 + 24576;      // 4N (16B aligned)
    float* sdst1  = ssrc1 + (size_t)N * 4;             // 4N
    float* ssrc2  = sdst1 + (size_t)N * 4;             // N
    float* sdst2  = ssrc2 + N;                         // N
    float* va     = sdst2 + N;                         // 256
    float* vb     = va + 256;                          // 256
    int*   deg    = (int*)(vb + 256);                  // N+1
    int*   rowptr = deg + M;                           // N+1
    int*   cursor = rowptr + M;                        // N
    int*   csum   = cursor + N;                        // 256
    int*   coff   = csum + 256;                        // 256
    int*   srcbuf = coff + 256;                        // Epad
    unsigned* minenc = (unsigned*)(srcbuf + Epad);     // 64

    hipMemsetAsync(deg, 0, (size_t)M * 4, stream);
    hipMemsetAsync(minenc, 0xFF, 64 * 4, stream);

    int nb16 = (N + 15) / 16;
    int nb32 = (N + 31) / 32;
    int nb4 = (N + 3) / 4;
    int nbh = (Etot + 255) / 256;

    pre_kernel<<<193, 256, 0, stream>>>(W1, W2, a_src2, a_dst2, W1s, W2s, va, vb);
    front_kernel<<<nb16 + nbh, 256, 0, stream>>>(x, W1s, a_src1, a_dst1, h1b, ssrc1, sdst1,
                                                 ei, deg, N, E, Etot, nb16);

    chunksum_kernel<<<nchunks, 256, 0, stream>>>(deg, csum, M);
    scanchunks_kernel<<<1, 256, 0, stream>>>(csum, coff, nchunks);
    rowptr_kernel<<<nchunks, 256, 0, stream>>>(deg, coff, rowptr, cursor, M, N);
    scatter_kernel<<<(Etot + 255) / 256, 256, 0, stream>>>(ei, cursor, srcbuf, E, Etot);

    agg1_kernel<<<nb4, 256, 0, stream>>>(rowptr, srcbuf, ssrc1, sdst1, h1b, b1,
                                         va, vb, x2b, ssrc2, sdst2, N);
    aggx_kernel<<<nb4, 256, 0, stream>>>(rowptr, srcbuf, ssrc2, sdst2, x2b, yb, N);
    gemm2min_kernel<<<nb32, 256, 0, stream>>>(yb, W2s, b2, minenc, N);
    decode_kernel<<<1, 64, 0, stream>>>(minenc, out);
}

// Round 12
// 358.519 us; speedup vs baseline: 1.4059x; 1.1243x over previous
//
#include <hip/hip_runtime.h>
#include <math.h>

typedef unsigned short ushort_t;
typedef __attribute__((ext_vector_type(8))) short bf16x8;
typedef __attribute__((ext_vector_type(4))) float f32x4;

// ---------- helpers ----------

__device__ inline unsigned fenc(float f) {
    unsigned u = __float_as_uint(f);
    return (u & 0x80000000u) ? ~u : (u | 0x80000000u);
}
__device__ inline float fdec(unsigned u) {
    return __uint_as_float((u & 0x80000000u) ? (u ^ 0x80000000u) : ~u);
}

__device__ inline float wrsum(float v) {
    #pragma unroll
    for (int m = 32; m; m >>= 1) v += __shfl_xor(v, m, 64);
    return v;
}
__device__ inline float lrelu(float x) { return x > 0.f ? x : 0.2f * x; }

__device__ inline ushort_t f2bf(float f) {
    unsigned u = __float_as_uint(f);
    u += 0x7FFFu + ((u >> 16) & 1u);      // round-to-nearest-even
    return (ushort_t)(u >> 16);
}
__device__ inline float bflo(unsigned u) { return __uint_as_float(u << 16); }
__device__ inline float bfhi(unsigned u) { return __uint_as_float(u & 0xFFFF0000u); }

// ---------- pre kernel: W1/W2 bf16 B-fragment swizzles + vab fold ----------
__global__ __launch_bounds__(256) void pre_kernel(const float* __restrict__ W1,
                                                  const float* __restrict__ W2,
                                                  const float* __restrict__ a_src2,
                                                  const float* __restrict__ a_dst2,
                                                  ushort_t* __restrict__ W1s,
                                                  ushort_t* __restrict__ W2s,
                                                  float* __restrict__ va,
                                                  float* __restrict__ vb) {
    int bid = blockIdx.x;
    int tid = threadIdx.x;
    if (bid < 128) {                       // W1 swizzle: 32768 elems
        int idx = bid * 256 + tid;
        int j = idx & 7;
        int lane = (idx >> 3) & 63;
        int ct = (idx >> 9) & 15;
        int kc = (idx >> 13) & 3;
        int k = kc * 32 + (lane >> 4) * 8 + j;
        int c = ct * 16 + (lane & 15);
        W1s[idx] = f2bf(W1[k * 256 + c]);
    } else if (bid < 192) {                // W2 swizzle: 16384 elems
        int idx = (bid - 128) * 256 + tid;
        int j = idx & 7;
        int lane = (idx >> 3) & 63;
        int ct = (idx >> 9) & 3;
        int kc = idx >> 11;
        int k = kc * 32 + (lane >> 4) * 8 + j;
        int c = ct * 16 + (lane & 15);
        W2s[idx] = f2bf(W2[k * 64 + c]);
    } else {                               // vab
        int k = tid;
        float sa = 0.f, sb = 0.f;
        #pragma unroll 8
        for (int c = 0; c < 64; c++) {
            float w = W2[k * 64 + c];
            sa += w * a_src2[c];
            sb += w * a_dst2[c];
        }
        va[k] = sa;
        vb[k] = sb;
    }
}

// ---------- front kernel: MFMA gemm1 (+scores1) merged with hist (+rank capture) ----------
__global__ __launch_bounds__(256) void front_kernel(const float* __restrict__ x,
                                                    const ushort_t* __restrict__ W1s,
                                                    const float* __restrict__ a_src,
                                                    const float* __restrict__ a_dst,
                                                    ushort_t* __restrict__ h1b,
                                                    float* __restrict__ ssrc,
                                                    float* __restrict__ sdst,
                                                    const int* __restrict__ ei,
                                                    int* __restrict__ deg,
                                                    int* __restrict__ rankb,
                                                    int N, int E, int Etot, int nb16) {
    __shared__ float ss[16 * 257];
    __shared__ float ps[256];
    int bid = blockIdx.x;
    int tid = threadIdx.x;

    if (bid >= nb16) {                     // ---- hist + rank ----
        int i = (bid - nb16) * 256 + tid;
        if (i < Etot) {
            int d = (i < E) ? ei[E + i] : (i - E);
            rankb[i] = atomicAdd(&deg[d], 1);
        }
        return;
    }

    // ---- gemm1 via MFMA ----
    int base = bid * 16;
    int lane = tid & 63, wv = tid >> 6;
    int m = lane & 15, q = lane >> 4;

    bool rowok = (base + m) < N;
    bf16x8 afrag[4];
    #pragma unroll
    for (int kc = 0; kc < 4; kc++) {
        float4 xa = make_float4(0.f, 0.f, 0.f, 0.f), xb = xa;
        if (rowok) {
            const float* xp = x + (size_t)(base + m) * 128 + kc * 32 + q * 8;
            xa = *(const float4*)xp;
            xb = *(const float4*)(xp + 4);
        }
        bf16x8 af;
        af[0] = (short)f2bf(xa.x); af[1] = (short)f2bf(xa.y);
        af[2] = (short)f2bf(xa.z); af[3] = (short)f2bf(xa.w);
        af[4] = (short)f2bf(xb.x); af[5] = (short)f2bf(xb.y);
        af[6] = (short)f2bf(xb.z); af[7] = (short)f2bf(xb.w);
        afrag[kc] = af;
    }

    #pragma unroll
    for (int t = 0; t < 4; t++) {
        int ct = wv * 4 + t;
        f32x4 acc = {0.f, 0.f, 0.f, 0.f};
        #pragma unroll
        for (int kc = 0; kc < 4; kc++) {
            bf16x8 bfrag = *(const bf16x8*)(W1s + (((size_t)(kc * 16 + ct) * 64 + lane) << 3));
            acc = __builtin_amdgcn_mfma_f32_16x16x32_bf16(afrag[kc], bfrag, acc, 0, 0, 0);
        }
        #pragma unroll
        for (int reg = 0; reg < 4; reg++) {
            ss[(q * 4 + reg) * 257 + ct * 16 + m] = acc[reg];
        }
    }
    __syncthreads();

    int dd = tid & 63, hh = tid >> 6;
    #pragma unroll
    for (int j = 0; j < 16; j++) {
        int n = base + j;
        if (n < N) h1b[(size_t)n * 256 + dd * 4 + hh] = f2bf(ss[j * 257 + tid]);
    }
    int j = tid & 15, hh2 = (tid >> 4) & 3, which = (tid >> 6) & 1, half = tid >> 7;
    const float* av = which ? a_dst : a_src;
    int cbase = hh2 * 64 + half * 32;
    float sum = 0.f;
    #pragma unroll
    for (int i = 0; i < 32; i++) {
        int ii = (i + 8 * hh2) & 31;
        sum += ss[j * 257 + cbase + ii] * av[cbase + ii];
    }
    ps[tid] = sum;
    __syncthreads();
    if (half == 0) {
        float tot = sum + ps[tid + 128];
        int n = base + j;
        if (n < N) (which ? sdst : ssrc)[n * 4 + hh2] = tot;
    }
}

// ---------- CSR scan chain ----------
__global__ __launch_bounds__(256) void chunksum_kernel(const int* __restrict__ deg,
                                                       int* __restrict__ csum, int M) {
    __shared__ int sm[256];
    int t = blockIdx.x * 256 + threadIdx.x;
    sm[threadIdx.x] = (t < M) ? deg[t] : 0;
    __syncthreads();
    for (int off = 128; off > 0; off >>= 1) {
        if (threadIdx.x < off) sm[threadIdx.x] += sm[threadIdx.x + off];
        __syncthreads();
    }
    if (threadIdx.x == 0) csum[blockIdx.x] = sm[0];
}

__global__ __launch_bounds__(256) void scanchunks_kernel(const int* __restrict__ csum,
                                                         int* __restrict__ coffset, int nchunks) {
    __shared__ int sm[256];
    int v = (threadIdx.x < nchunks) ? csum[threadIdx.x] : 0;
    sm[threadIdx.x] = v;
    __syncthreads();
    for (int off = 1; off < 256; off <<= 1) {
        int a = (threadIdx.x >= off) ? sm[threadIdx.x - off] : 0;
        __syncthreads();
        sm[threadIdx.x] += a;
        __syncthreads();
    }
    coffset[threadIdx.x] = sm[threadIdx.x] - v;
}

__global__ __launch_bounds__(256) void rowptr_kernel(const int* __restrict__ deg,
                                                     const int* __restrict__ coffset,
                                                     int* __restrict__ rowptr, int M) {
    __shared__ int sm[256];
    int t = blockIdx.x * 256 + threadIdx.x;
    int v = (t < M) ? deg[t] : 0;
    sm[threadIdx.x] = v;
    __syncthreads();
    for (int off = 1; off < 256; off <<= 1) {
        int a = (threadIdx.x >= off) ? sm[threadIdx.x - off] : 0;
        __syncthreads();
        sm[threadIdx.x] += a;
        __syncthreads();
    }
    if (t < M) rowptr[t] = coffset[blockIdx.x] + sm[threadIdx.x] - v;
}

// ---------- scatter (atomic-free via ranks) ----------
__global__ __launch_bounds__(256) void scatter_kernel(const int* __restrict__ ei,
                                                      const int* __restrict__ rowptr,
                                                      const int* __restrict__ rankb,
                                                      int* __restrict__ srcbuf, int E, int Etot) {
    int i = blockIdx.x * 256 + threadIdx.x;
    if (i >= Etot) return;
    int s, d;
    if (i < E) { s = ei[i]; d = ei[E + i]; } else { s = d = i - E; }
    srcbuf[rowptr[d] + rankb[i]] = s;
}

// ---------- layer-1 aggregation: plain-exp softmax (scores bounded), bf16 512B rows ----------
__global__ __launch_bounds__(256) void agg1_kernel(const int* __restrict__ rowptr,
                                                   const int* __restrict__ srcbuf,
                                                   const float* __restrict__ ssrc,
                                                   const float* __restrict__ sdst,
                                                   const ushort_t* __restrict__ h1b,
                                                   const float* __restrict__ b1,
                                                   const float* __restrict__ va,
                                                   const float* __restrict__ vb,
                                                   ushort_t* __restrict__ x2b,
                                                   float* __restrict__ ssrc2,
                                                   float* __restrict__ sdst2, int N) {
    __shared__ int    s_sh[4][64];
    __shared__ float4 w_sh[4][64];
    int lane = threadIdx.x & 63, w = threadIdx.x >> 6;
    int d = blockIdx.x * 4 + w;
    if (d >= N) return;
    int row = rowptr[d], end = rowptr[d + 1];
    float4 sd = *(const float4*)(sdst + d * 4);
    float l0 = 0.f, l1 = 0.f, l2 = 0.f, l3 = 0.f;
    float a0 = 0.f, a1 = 0.f, a2 = 0.f, a3 = 0.f;

    for (int base = row; base < end; base += 64) {
        int cnt = min(64, end - base);
        bool valid = lane < cnt;
        int s = valid ? srcbuf[base + lane] : 0;
        float4 ssv = *(const float4*)(ssrc + s * 4);
        float w0 = valid ? __expf(lrelu(ssv.x + sd.x)) : 0.f;
        float w1 = valid ? __expf(lrelu(ssv.y + sd.y)) : 0.f;
        float w2 = valid ? __expf(lrelu(ssv.z + sd.z)) : 0.f;
        float w3 = valid ? __expf(lrelu(ssv.w + sd.w)) : 0.f;
        l0 += wrsum(w0);  l1 += wrsum(w1);
        l2 += wrsum(w2);  l3 += wrsum(w3);
        s_sh[w][lane] = s;
        w_sh[w][lane] = make_float4(w0, w1, w2, w3);
        // wave-private LDS; lockstep wave, no barrier needed
        int cnt4 = (cnt + 3) & ~3;
        for (int j = 0; j < cnt4; j += 4) {
            int sj0 = s_sh[w][j], sj1 = s_sh[w][j + 1], sj2 = s_sh[w][j + 2], sj3 = s_sh[w][j + 3];
            float4 wj0 = w_sh[w][j], wj1 = w_sh[w][j + 1], wj2 = w_sh[w][j + 2], wj3 = w_sh[w][j + 3];
            uint2 u0 = *(const uint2*)(h1b + (size_t)sj0 * 256 + lane * 4);
            uint2 u1 = *(const uint2*)(h1b + (size_t)sj1 * 256 + lane * 4);
            uint2 u2 = *(const uint2*)(h1b + (size_t)sj2 * 256 + lane * 4);
            uint2 u3 = *(const uint2*)(h1b + (size_t)sj3 * 256 + lane * 4);
            a0 += wj0.x * bflo(u0.x); a1 += wj0.y * bfhi(u0.x);
            a2 += wj0.z * bflo(u0.y); a3 += wj0.w * bfhi(u0.y);
            a0 += wj1.x * bflo(u1.x); a1 += wj1.y * bfhi(u1.x);
            a2 += wj1.z * bflo(u1.y); a3 += wj1.w * bfhi(u1.y);
            a0 += wj2.x * bflo(u2.x); a1 += wj2.y * bfhi(u2.x);
            a2 += wj2.z * bflo(u2.y); a3 += wj2.w * bfhi(u2.y);
            a0 += wj3.x * bflo(u3.x); a1 += wj3.y * bfhi(u3.x);
            a2 += wj3.z * bflo(u3.y); a3 += wj3.w * bfhi(u3.y);
        }
    }
    float v0 = a0 / l0 + b1[lane];
    float v1 = a1 / l1 + b1[64 + lane];
    float v2 = a2 / l2 + b1[128 + lane];
    float v3 = a3 / l3 + b1[192 + lane];
    v0 = v0 > 0.f ? v0 : __expf(v0) - 1.f;
    v1 = v1 > 0.f ? v1 : __expf(v1) - 1.f;
    v2 = v2 > 0.f ? v2 : __expf(v2) - 1.f;
    v3 = v3 > 0.f ? v3 : __expf(v3) - 1.f;
    ushort_t* xp = x2b + (size_t)d * 256;
    xp[lane] = f2bf(v0); xp[64 + lane] = f2bf(v1);
    xp[128 + lane] = f2bf(v2); xp[192 + lane] = f2bf(v3);
    float sa = v0 * va[lane] + v1 * va[64 + lane] + v2 * va[128 + lane] + v3 * va[192 + lane];
    float sb = v0 * vb[lane] + v1 * vb[64 + lane] + v2 * vb[128 + lane] + v3 * vb[192 + lane];
    sa = wrsum(sa);
    sb = wrsum(sb);
    if (lane == 0) { ssrc2[d] = sa; sdst2[d] = sb; }
}

// ---------- layer-2 feature aggregation (pre-GEMM, via linearity), plain-exp ----------
__global__ __launch_bounds__(256) void aggx_kernel(const int* __restrict__ rowptr,
                                                   const int* __restrict__ srcbuf,
                                                   const float* __restrict__ ssrc,
                                                   const float* __restrict__ sdst,
                                                   const ushort_t* __restrict__ x2b,
                                                   ushort_t* __restrict__ yb, int N) {
    __shared__ int   s_sh[4][64];
    __shared__ float w_sh[4][64];
    int lane = threadIdx.x & 63, w = threadIdx.x >> 6;
    int d = blockIdx.x * 4 + w;
    if (d >= N) return;
    int row = rowptr[d], end = rowptr[d + 1];
    float sdv = sdst[d];
    float l = 0.f;
    float a0 = 0.f, a1 = 0.f, a2 = 0.f, a3 = 0.f;
    for (int base = row; base < end; base += 64) {
        int cnt = min(64, end - base);
        bool valid = lane < cnt;
        int s = valid ? srcbuf[base + lane] : 0;
        float wt = valid ? __expf(lrelu(ssrc[s] + sdv)) : 0.f;
        l += wrsum(wt);
        s_sh[w][lane] = s;
        w_sh[w][lane] = wt;
        int cnt4 = (cnt + 3) & ~3;
        for (int j = 0; j < cnt4; j += 4) {
            int sj0 = s_sh[w][j], sj1 = s_sh[w][j + 1], sj2 = s_sh[w][j + 2], sj3 = s_sh[w][j + 3];
            float wj0 = w_sh[w][j], wj1 = w_sh[w][j + 1], wj2 = w_sh[w][j + 2], wj3 = w_sh[w][j + 3];
            uint2 u0 = *(const uint2*)(x2b + (size_t)sj0 * 256 + lane * 4);
            uint2 u1 = *(const uint2*)(x2b + (size_t)sj1 * 256 + lane * 4);
            uint2 u2 = *(const uint2*)(x2b + (size_t)sj2 * 256 + lane * 4);
            uint2 u3 = *(const uint2*)(x2b + (size_t)sj3 * 256 + lane * 4);
            a0 += wj0 * bflo(u0.x); a1 += wj0 * bfhi(u0.x);
            a2 += wj0 * bflo(u0.y); a3 += wj0 * bfhi(u0.y);
            a0 += wj1 * bflo(u1.x); a1 += wj1 * bfhi(u1.x);
            a2 += wj1 * bflo(u1.y); a3 += wj1 * bfhi(u1.y);
            a0 += wj2 * bflo(u2.x); a1 += wj2 * bfhi(u2.x);
            a2 += wj2 * bflo(u2.y); a3 += wj2 * bfhi(u2.y);
            a0 += wj3 * bflo(u3.x); a1 += wj3 * bfhi(u3.x);
            a2 += wj3 * bflo(u3.y); a3 += wj3 * bfhi(u3.y);
        }
    }
    float inv = 1.f / l;
    unsigned p0 = (unsigned)f2bf(a0 * inv) | ((unsigned)f2bf(a1 * inv) << 16);
    unsigned p1 = (unsigned)f2bf(a2 * inv) | ((unsigned)f2bf(a3 * inv) << 16);
    *(uint2*)(yb + (size_t)d * 256 + lane * 4) = make_uint2(p0, p1);
}

// ---------- final GEMM via MFMA: (y @ W2 + b2), fused global min; 32 nodes/block ----------
__global__ __launch_bounds__(256) void gemm2min_kernel(const ushort_t* __restrict__ yb,
                                                       const ushort_t* __restrict__ W2s,
                                                       const float* __restrict__ b2,
                                                       unsigned* __restrict__ minenc, int N) {
    int base = blockIdx.x * 32;
    int tid = threadIdx.x;
    int lane = tid & 63, wv = tid >> 6;
    int m = lane & 15, q = lane >> 4;
    int c = wv * 16 + m;
    float bc = b2[c];
    float mv = INFINITY;

    #pragma unroll
    for (int h = 0; h < 2; h++) {
        int rbase = base + h * 16;
        bool rowok = (rbase + m) < N;
        const ushort_t* yrow = yb + (size_t)(rbase + m) * 256;
        f32x4 acc = {0.f, 0.f, 0.f, 0.f};
        #pragma unroll
        for (int kc = 0; kc < 8; kc++) {
            bf16x8 af = {0, 0, 0, 0, 0, 0, 0, 0};
            if (rowok) af = *(const bf16x8*)(yrow + kc * 32 + q * 8);
            bf16x8 bf = *(const bf16x8*)(W2s + (((size_t)(kc * 4 + wv) * 64 + lane) << 3));
            acc = __builtin_amdgcn_mfma_f32_16x16x32_bf16(af, bf, acc, 0, 0, 0);
        }
        #pragma unroll
        for (int reg = 0; reg < 4; reg++) {
            int n = rbase + q * 4 + reg;
            if (n < N) mv = fminf(mv, acc[reg] + bc);
        }
    }
    mv = fminf(mv, __shfl_xor(mv, 16, 64));
    mv = fminf(mv, __shfl_xor(mv, 32, 64));
    if (q == 0) atomicMin(&minenc[c], fenc(mv));
}

__global__ void decode_kernel(const unsigned* __restrict__ minenc, float* __restrict__ out) {
    int d = threadIdx.x;
    if (d < 64) out[d] = fdec(minenc[d]);
}

// ---------- launch ----------
extern "C" void kernel_launch(void* const* d_in, const int* in_sizes, int n_in,
                              void* d_out, int out_size, void* d_ws, size_t ws_size,
                              hipStream_t stream) {
    const float* x      = (const float*)d_in[0];
    const int*   ei     = (const int*)d_in[1];
    const float* W1     = (const float*)d_in[2];
    const float* a_src1 = (const float*)d_in[3];
    const float* a_dst1 = (const float*)d_in[4];
    const float* b1     = (const float*)d_in[5];
    const float* W2     = (const float*)d_in[6];
    const float* a_src2 = (const float*)d_in[7];
    const float* a_dst2 = (const float*)d_in[8];
    const float* b2     = (const float*)d_in[9];
    float* out = (float*)d_out;

    const int N = in_sizes[0] / 128;
    const int E = in_sizes[1] / 2;
    const int Etot = E + N;
    const int Epad = Etot + 64;
    const int M = N + 1;
    const int nchunks = (M + 255) / 256;   // <= 256 for N <= ~65k

    // workspace layout (4-byte words; N divisible by 4 keeps 16B alignment)
    float* ws = (float*)d_ws;
    ushort_t* h1b = (ushort_t*)ws;                     // N*256 bf16 = N*128 words
    ushort_t* x2b = (ushort_t*)(ws + (size_t)N * 128); // N*256 bf16
    ushort_t* yb  = (ushort_t*)(ws + (size_t)N * 256); // N*256 bf16
    ushort_t* W1s = (ushort_t*)(ws + (size_t)N * 384); // 32768 bf16 = 16384 words
    ushort_t* W2s = (ushort_t*)(ws + (size_t)N * 384 + 16384); // 16384 bf16 = 8192 words
    float* ssrc1  = ws + (size_t)N * 384 + 24576;      // 4N (16B aligned)
    float* sdst1  = ssrc1 + (size_t)N * 4;             // 4N
    float* ssrc2  = sdst1 + (size_t)N * 4;             // N
    float* sdst2  = ssrc2 + N;                         // N
    float* va     = sdst2 + N;                         // 256
    float* vb     = va + 256;                          // 256
    int*   deg    = (int*)(vb + 256);                  // N+1
    int*   rowptr = deg + M;                           // N+1
    int*   csum   = rowptr + M;                        // 256
    int*   coff   = csum + 256;                        // 256
    int*   srcbuf = coff + 256;                        // Epad
    int*   rankb  = srcbuf + Epad;                     // Epad
    unsigned* minenc = (unsigned*)(rankb + Epad);      // 64

    hipMemsetAsync(deg, 0, (size_t)M * 4, stream);
    hipMemsetAsync(minenc, 0xFF, 64 * 4, stream);

    int nb16 = (N + 15) / 16;
    int nb32 = (N + 31) / 32;
    int nb4 = (N + 3) / 4;
    int nbh = (Etot + 255) / 256;

    pre_kernel<<<193, 256, 0, stream>>>(W1, W2, a_src2, a_dst2, W1s, W2s, va, vb);
    front_kernel<<<nb16 + nbh, 256, 0, stream>>>(x, W1s, a_src1, a_dst1, h1b, ssrc1, sdst1,
                                                 ei, deg, rankb, N, E, Etot, nb16);

    chunksum_kernel<<<nchunks, 256, 0, stream>>>(deg, csum, M);
    scanchunks_kernel<<<1, 256, 0, stream>>>(csum, coff, nchunks);
    rowptr_kernel<<<nchunks, 256, 0, stream>>>(deg, coff, rowptr, M);
    scatter_kernel<<<(Etot + 255) / 256, 256, 0, stream>>>(ei, rowptr, rankb, srcbuf, E, Etot);

    agg1_kernel<<<nb4, 256, 0, stream>>>(rowptr, srcbuf, ssrc1, sdst1, h1b, b1,
                                         va, vb, x2b, ssrc2, sdst2, N);
    aggx_kernel<<<nb4, 256, 0, stream>>>(rowptr, srcbuf, ssrc2, sdst2, x2b, yb, N);
    gemm2min_kernel<<<nb32, 256, 0, stream>>>(yb, W2s, b2, minenc, N);
    decode_kernel<<<1, 64, 0, stream>>>(minenc, out);
}

// Round 13
// 311.646 us; speedup vs baseline: 1.6173x; 1.1504x over previous
//
#include <hip/hip_runtime.h>
#include <math.h>

typedef unsigned short ushort_t;
typedef __attribute__((ext_vector_type(8))) short bf16x8;
typedef __attribute__((ext_vector_type(4))) float f32x4;

// ---------- helpers ----------

__device__ inline unsigned fenc(float f) {
    unsigned u = __float_as_uint(f);
    return (u & 0x80000000u) ? ~u : (u | 0x80000000u);
}
__device__ inline float fdec(unsigned u) {
    return __uint_as_float((u & 0x80000000u) ? (u ^ 0x80000000u) : ~u);
}

__device__ inline float wrsum(float v) {
    #pragma unroll
    for (int m = 32; m; m >>= 1) v += __shfl_xor(v, m, 64);
    return v;
}
__device__ inline float lrelu(float x) { return x > 0.f ? x : 0.2f * x; }

__device__ inline ushort_t f2bf(float f) {
    unsigned u = __float_as_uint(f);
    u += 0x7FFFu + ((u >> 16) & 1u);      // round-to-nearest-even
    return (ushort_t)(u >> 16);
}
__device__ inline float bflo(unsigned u) { return __uint_as_float(u << 16); }
__device__ inline float bfhi(unsigned u) { return __uint_as_float(u & 0xFFFF0000u); }

// ---------- pre kernel: W1/W2 bf16 B-fragment swizzles + vab fold ----------
__global__ __launch_bounds__(256) void pre_kernel(const float* __restrict__ W1,
                                                  const float* __restrict__ W2,
                                                  const float* __restrict__ a_src2,
                                                  const float* __restrict__ a_dst2,
                                                  ushort_t* __restrict__ W1s,
                                                  ushort_t* __restrict__ W2s,
                                                  float* __restrict__ va,
                                                  float* __restrict__ vb) {
    int bid = blockIdx.x;
    int tid = threadIdx.x;
    if (bid < 128) {                       // W1 swizzle: 32768 elems
        int idx = bid * 256 + tid;
        int j = idx & 7;
        int lane = (idx >> 3) & 63;
        int ct = (idx >> 9) & 15;
        int kc = (idx >> 13) & 3;
        int k = kc * 32 + (lane >> 4) * 8 + j;
        int c = ct * 16 + (lane & 15);
        W1s[idx] = f2bf(W1[k * 256 + c]);
    } else if (bid < 192) {                // W2 swizzle: 16384 elems
        int idx = (bid - 128) * 256 + tid;
        int j = idx & 7;
        int lane = (idx >> 3) & 63;
        int ct = (idx >> 9) & 3;
        int kc = idx >> 11;
        int k = kc * 32 + (lane >> 4) * 8 + j;
        int c = ct * 16 + (lane & 15);
        W2s[idx] = f2bf(W2[k * 64 + c]);
    } else {                               // vab
        int k = tid;
        float sa = 0.f, sb = 0.f;
        #pragma unroll 8
        for (int c = 0; c < 64; c++) {
            float w = W2[k * 64 + c];
            sa += w * a_src2[c];
            sb += w * a_dst2[c];
        }
        va[k] = sa;
        vb[k] = sb;
    }
}

// ---------- front kernel: MFMA gemm1 (+scores1) merged with hist (+rank capture) ----------
__global__ __launch_bounds__(256) void front_kernel(const float* __restrict__ x,
                                                    const ushort_t* __restrict__ W1s,
                                                    const float* __restrict__ a_src,
                                                    const float* __restrict__ a_dst,
                                                    ushort_t* __restrict__ h1b,
                                                    float* __restrict__ ssrc,
                                                    float* __restrict__ sdst,
                                                    const int* __restrict__ ei,
                                                    int* __restrict__ deg,
                                                    int* __restrict__ rankb,
                                                    int N, int E, int Etot, int nb16) {
    __shared__ float ss[16 * 257];
    __shared__ float ps[256];
    int bid = blockIdx.x;
    int tid = threadIdx.x;

    if (bid >= nb16) {                     // ---- hist + rank ----
        int i = (bid - nb16) * 256 + tid;
        if (i < Etot) {
            int d = (i < E) ? ei[E + i] : (i - E);
            rankb[i] = atomicAdd(&deg[d], 1);
        }
        return;
    }

    // ---- gemm1 via MFMA ----
    int base = bid * 16;
    int lane = tid & 63, wv = tid >> 6;
    int m = lane & 15, q = lane >> 4;

    bool rowok = (base + m) < N;
    bf16x8 afrag[4];
    #pragma unroll
    for (int kc = 0; kc < 4; kc++) {
        float4 xa = make_float4(0.f, 0.f, 0.f, 0.f), xb = xa;
        if (rowok) {
            const float* xp = x + (size_t)(base + m) * 128 + kc * 32 + q * 8;
            xa = *(const float4*)xp;
            xb = *(const float4*)(xp + 4);
        }
        bf16x8 af;
        af[0] = (short)f2bf(xa.x); af[1] = (short)f2bf(xa.y);
        af[2] = (short)f2bf(xa.z); af[3] = (short)f2bf(xa.w);
        af[4] = (short)f2bf(xb.x); af[5] = (short)f2bf(xb.y);
        af[6] = (short)f2bf(xb.z); af[7] = (short)f2bf(xb.w);
        afrag[kc] = af;
    }

    #pragma unroll
    for (int t = 0; t < 4; t++) {
        int ct = wv * 4 + t;
        f32x4 acc = {0.f, 0.f, 0.f, 0.f};
        #pragma unroll
        for (int kc = 0; kc < 4; kc++) {
            bf16x8 bfrag = *(const bf16x8*)(W1s + (((size_t)(kc * 16 + ct) * 64 + lane) << 3));
            acc = __builtin_amdgcn_mfma_f32_16x16x32_bf16(afrag[kc], bfrag, acc, 0, 0, 0);
        }
        #pragma unroll
        for (int reg = 0; reg < 4; reg++) {
            ss[(q * 4 + reg) * 257 + ct * 16 + m] = acc[reg];
        }
    }
    __syncthreads();

    int dd = tid & 63, hh = tid >> 6;
    #pragma unroll
    for (int j = 0; j < 16; j++) {
        int n = base + j;
        if (n < N) h1b[(size_t)n * 256 + dd * 4 + hh] = f2bf(ss[j * 257 + tid]);
    }
    int j = tid & 15, hh2 = (tid >> 4) & 3, which = (tid >> 6) & 1, half = tid >> 7;
    const float* av = which ? a_dst : a_src;
    int cbase = hh2 * 64 + half * 32;
    float sum = 0.f;
    #pragma unroll
    for (int i = 0; i < 32; i++) {
        int ii = (i + 8 * hh2) & 31;
        sum += ss[j * 257 + cbase + ii] * av[cbase + ii];
    }
    ps[tid] = sum;
    __syncthreads();
    if (half == 0) {
        float tot = sum + ps[tid + 128];
        int n = base + j;
        if (n < N) (which ? sdst : ssrc)[n * 4 + hh2] = tot;
    }
}

// ---------- CSR scan chain ----------
__global__ __launch_bounds__(256) void chunksum_kernel(const int* __restrict__ deg,
                                                       int* __restrict__ csum, int M) {
    __shared__ int sm[256];
    int t = blockIdx.x * 256 + threadIdx.x;
    sm[threadIdx.x] = (t < M) ? deg[t] : 0;
    __syncthreads();
    for (int off = 128; off > 0; off >>= 1) {
        if (threadIdx.x < off) sm[threadIdx.x] += sm[threadIdx.x + off];
        __syncthreads();
    }
    if (threadIdx.x == 0) csum[blockIdx.x] = sm[0];
}

__global__ __launch_bounds__(256) void scanchunks_kernel(const int* __restrict__ csum,
                                                         int* __restrict__ coffset, int nchunks) {
    __shared__ int sm[256];
    int v = (threadIdx.x < nchunks) ? csum[threadIdx.x] : 0;
    sm[threadIdx.x] = v;
    __syncthreads();
    for (int off = 1; off < 256; off <<= 1) {
        int a = (threadIdx.x >= off) ? sm[threadIdx.x - off] : 0;
        __syncthreads();
        sm[threadIdx.x] += a;
        __syncthreads();
    }
    coffset[threadIdx.x] = sm[threadIdx.x] - v;
}

__global__ __launch_bounds__(256) void rowptr_kernel(const int* __restrict__ deg,
                                                     const int* __restrict__ coffset,
                                                     int* __restrict__ rowptr, int M) {
    __shared__ int sm[256];
    int t = blockIdx.x * 256 + threadIdx.x;
    int v = (t < M) ? deg[t] : 0;
    sm[threadIdx.x] = v;
    __syncthreads();
    for (int off = 1; off < 256; off <<= 1) {
        int a = (threadIdx.x >= off) ? sm[threadIdx.x - off] : 0;
        __syncthreads();
        sm[threadIdx.x] += a;
        __syncthreads();
    }
    if (t < M) rowptr[t] = coffset[blockIdx.x] + sm[threadIdx.x] - v;
}

// ---------- scatter (atomic-free via ranks) ----------
__global__ __launch_bounds__(256) void scatter_kernel(const int* __restrict__ ei,
                                                      const int* __restrict__ rowptr,
                                                      const int* __restrict__ rankb,
                                                      int* __restrict__ srcbuf, int E, int Etot) {
    int i = blockIdx.x * 256 + threadIdx.x;
    if (i >= Etot) return;
    int s, d;
    if (i < E) { s = ei[i]; d = ei[E + i]; } else { s = d = i - E; }
    srcbuf[rowptr[d] + rankb[i]] = s;
}

// ---------- layer-1 aggregation: plain-exp softmax, bf16 512B rows ----------
__global__ __launch_bounds__(256) void agg1_kernel(const int* __restrict__ rowptr,
                                                   const int* __restrict__ srcbuf,
                                                   const float* __restrict__ ssrc,
                                                   const float* __restrict__ sdst,
                                                   const ushort_t* __restrict__ h1b,
                                                   const float* __restrict__ b1,
                                                   const float* __restrict__ va,
                                                   const float* __restrict__ vb,
                                                   ushort_t* __restrict__ x2b,
                                                   float* __restrict__ ssrc2,
                                                   float* __restrict__ sdst2, int N) {
    __shared__ int    s_sh[4][64];
    __shared__ float4 w_sh[4][64];
    int lane = threadIdx.x & 63, w = threadIdx.x >> 6;
    int d = blockIdx.x * 4 + w;
    if (d >= N) return;
    int row = rowptr[d], end = rowptr[d + 1];
    float4 sd = *(const float4*)(sdst + d * 4);
    float l0 = 0.f, l1 = 0.f, l2 = 0.f, l3 = 0.f;
    float a0 = 0.f, a1 = 0.f, a2 = 0.f, a3 = 0.f;

    for (int base = row; base < end; base += 64) {
        int cnt = min(64, end - base);
        bool valid = lane < cnt;
        int s = valid ? srcbuf[base + lane] : 0;
        float4 ssv = *(const float4*)(ssrc + s * 4);
        float w0 = valid ? __expf(lrelu(ssv.x + sd.x)) : 0.f;
        float w1 = valid ? __expf(lrelu(ssv.y + sd.y)) : 0.f;
        float w2 = valid ? __expf(lrelu(ssv.z + sd.z)) : 0.f;
        float w3 = valid ? __expf(lrelu(ssv.w + sd.w)) : 0.f;
        l0 += wrsum(w0);  l1 += wrsum(w1);
        l2 += wrsum(w2);  l3 += wrsum(w3);
        s_sh[w][lane] = s;
        w_sh[w][lane] = make_float4(w0, w1, w2, w3);
        // wave-private LDS; lockstep wave, no barrier needed
        int cnt4 = (cnt + 3) & ~3;
        for (int j = 0; j < cnt4; j += 4) {
            int sj0 = s_sh[w][j], sj1 = s_sh[w][j + 1], sj2 = s_sh[w][j + 2], sj3 = s_sh[w][j + 3];
            float4 wj0 = w_sh[w][j], wj1 = w_sh[w][j + 1], wj2 = w_sh[w][j + 2], wj3 = w_sh[w][j + 3];
            uint2 u0 = *(const uint2*)(h1b + (size_t)sj0 * 256 + lane * 4);
            uint2 u1 = *(const uint2*)(h1b + (size_t)sj1 * 256 + lane * 4);
            uint2 u2 = *(const uint2*)(h1b + (size_t)sj2 * 256 + lane * 4);
            uint2 u3 = *(const uint2*)(h1b + (size_t)sj3 * 256 + lane * 4);
            a0 += wj0.x * bflo(u0.x); a1 += wj0.y * bfhi(u0.x);
            a2 += wj0.z * bflo(u0.y); a3 += wj0.w * bfhi(u0.y);
            a0 += wj1.x * bflo(u1.x); a1 += wj1.y * bfhi(u1.x);
            a2 += wj1.z * bflo(u1.y); a3 += wj1.w * bfhi(u1.y);
            a0 += wj2.x * bflo(u2.x); a1 += wj2.y * bfhi(u2.x);
            a2 += wj2.z * bflo(u2.y); a3 += wj2.w * bfhi(u2.y);
            a0 += wj3.x * bflo(u3.x); a1 += wj3.y * bfhi(u3.x);
            a2 += wj3.z * bflo(u3.y); a3 += wj3.w * bfhi(u3.y);
        }
    }
    float v0 = a0 / l0 + b1[lane];
    float v1 = a1 / l1 + b1[64 + lane];
    float v2 = a2 / l2 + b1[128 + lane];
    float v3 = a3 / l3 + b1[192 + lane];
    v0 = v0 > 0.f ? v0 : __expf(v0) - 1.f;
    v1 = v1 > 0.f ? v1 : __expf(v1) - 1.f;
    v2 = v2 > 0.f ? v2 : __expf(v2) - 1.f;
    v3 = v3 > 0.f ? v3 : __expf(v3) - 1.f;
    ushort_t* xp = x2b + (size_t)d * 256;
    xp[lane] = f2bf(v0); xp[64 + lane] = f2bf(v1);
    xp[128 + lane] = f2bf(v2); xp[192 + lane] = f2bf(v3);
    float sa = v0 * va[lane] + v1 * va[64 + lane] + v2 * va[128 + lane] + v3 * va[192 + lane];
    float sb = v0 * vb[lane] + v1 * vb[64 + lane] + v2 * vb[128 + lane] + v3 * vb[192 + lane];
    sa = wrsum(sa);
    sb = wrsum(sb);
    if (lane == 0) { ssrc2[d] = sa; sdst2[d] = sb; }
}

// ---------- gemmz via MFMA: z = x2b @ W2 + b2 (fp32, N x 64) ----------
__global__ __launch_bounds__(256) void gemmz_kernel(const ushort_t* __restrict__ x2b,
                                                    const ushort_t* __restrict__ W2s,
                                                    const float* __restrict__ b2,
                                                    float* __restrict__ z, int N) {
    int base = blockIdx.x * 32;
    int tid = threadIdx.x;
    int lane = tid & 63, wv = tid >> 6;
    int m = lane & 15, q = lane >> 4;
    int c = wv * 16 + m;
    float bc = b2[c];

    #pragma unroll
    for (int h = 0; h < 2; h++) {
        int rbase = base + h * 16;
        bool rowok = (rbase + m) < N;
        const ushort_t* xrow = x2b + (size_t)(rbase + m) * 256;
        f32x4 acc = {0.f, 0.f, 0.f, 0.f};
        #pragma unroll
        for (int kc = 0; kc < 8; kc++) {
            bf16x8 af = {0, 0, 0, 0, 0, 0, 0, 0};
            if (rowok) af = *(const bf16x8*)(xrow + kc * 32 + q * 8);
            bf16x8 bf = *(const bf16x8*)(W2s + (((size_t)(kc * 4 + wv) * 64 + lane) << 3));
            acc = __builtin_amdgcn_mfma_f32_16x16x32_bf16(af, bf, acc, 0, 0, 0);
        }
        #pragma unroll
        for (int reg = 0; reg < 4; reg++) {
            int n = rbase + q * 4 + reg;
            if (n < N) z[(size_t)n * 64 + c] = acc[reg] + bc;
        }
    }
}

// ---------- layer-2 aggregation over z (256B fp32 rows) + fused global min ----------
__global__ __launch_bounds__(256) void aggz_kernel(const int* __restrict__ rowptr,
                                                   const int* __restrict__ srcbuf,
                                                   const float* __restrict__ ssrc,
                                                   const float* __restrict__ sdst,
                                                   const float* __restrict__ z,
                                                   unsigned* __restrict__ minenc, int N) {
    __shared__ int   s_sh[4][64];
    __shared__ float w_sh[4][64];
    __shared__ float sm[256];
    int lane = threadIdx.x & 63, w = threadIdx.x >> 6;
    float minv = INFINITY;

    for (int d0 = blockIdx.x * 4; d0 < N; d0 += gridDim.x * 4) {
        int d = d0 + w;
        if (d < N) {
            int row = rowptr[d], end = rowptr[d + 1];
            float sdv = sdst[d];
            float l = 0.f;
            float a0 = 0.f, a1 = 0.f, a2 = 0.f, a3 = 0.f;
            for (int base = row; base < end; base += 64) {
                int cnt = min(64, end - base);
                bool valid = lane < cnt;
                int s = valid ? srcbuf[base + lane] : 0;
                float wt = valid ? __expf(lrelu(ssrc[s] + sdv)) : 0.f;
                l += wrsum(wt);
                s_sh[w][lane] = s;
                w_sh[w][lane] = wt;
                // wave-private LDS; lockstep wave
                int cnt4 = (cnt + 3) & ~3;
                for (int j = 0; j < cnt4; j += 4) {
                    int sj0 = s_sh[w][j], sj1 = s_sh[w][j + 1];
                    int sj2 = s_sh[w][j + 2], sj3 = s_sh[w][j + 3];
                    float wj0 = w_sh[w][j], wj1 = w_sh[w][j + 1];
                    float wj2 = w_sh[w][j + 2], wj3 = w_sh[w][j + 3];
                    float z0 = z[(size_t)sj0 * 64 + lane];
                    float z1 = z[(size_t)sj1 * 64 + lane];
                    float z2 = z[(size_t)sj2 * 64 + lane];
                    float z3 = z[(size_t)sj3 * 64 + lane];
                    a0 += wj0 * z0; a1 += wj1 * z1;
                    a2 += wj2 * z2; a3 += wj3 * z3;
                }
            }
            float out = ((a0 + a1) + (a2 + a3)) / l;   // b2 already folded into z
            minv = fminf(minv, out);
        }
    }
    sm[threadIdx.x] = minv;
    __syncthreads();
    if (w == 0) {
        float v = fminf(fminf(sm[lane], sm[64 + lane]), fminf(sm[128 + lane], sm[192 + lane]));
        atomicMin(&minenc[lane], fenc(v));
    }
}

__global__ void decode_kernel(const unsigned* __restrict__ minenc, float* __restrict__ out) {
    int d = threadIdx.x;
    if (d < 64) out[d] = fdec(minenc[d]);
}

// ---------- launch ----------
extern "C" void kernel_launch(void* const* d_in, const int* in_sizes, int n_in,
                              void* d_out, int out_size, void* d_ws, size_t ws_size,
                              hipStream_t stream) {
    const float* x      = (const float*)d_in[0];
    const int*   ei     = (const int*)d_in[1];
    const float* W1     = (const float*)d_in[2];
    const float* a_src1 = (const float*)d_in[3];
    const float* a_dst1 = (const float*)d_in[4];
    const float* b1     = (const float*)d_in[5];
    const float* W2     = (const float*)d_in[6];
    const float* a_src2 = (const float*)d_in[7];
    const float* a_dst2 = (const float*)d_in[8];
    const float* b2     = (const float*)d_in[9];
    float* out = (float*)d_out;

    const int N = in_sizes[0] / 128;
    const int E = in_sizes[1] / 2;
    const int Etot = E + N;
    const int Epad = Etot + 64;
    const int M = N + 1;
    const int nchunks = (M + 255) / 256;   // <= 256 for N <= ~65k

    // workspace layout (4-byte words; N divisible by 4 keeps 16B alignment)
    float* ws = (float*)d_ws;
    ushort_t* h1b = (ushort_t*)ws;                     // N*256 bf16 = N*128 words
    ushort_t* x2b = (ushort_t*)(ws + (size_t)N * 128); // N*256 bf16
    float* z      = ws + (size_t)N * 256;              // N*64 fp32
    ushort_t* W1s = (ushort_t*)(ws + (size_t)N * 320); // 32768 bf16 = 16384 words
    ushort_t* W2s = (ushort_t*)(ws + (size_t)N * 320 + 16384); // 16384 bf16 = 8192 words
    float* ssrc1  = ws + (size_t)N * 320 + 24576;      // 4N (16B aligned)
    float* sdst1  = ssrc1 + (size_t)N * 4;             // 4N
    float* ssrc2  = sdst1 + (size_t)N * 4;             // N
    float* sdst2  = ssrc2 + N;                         // N
    float* va     = sdst2 + N;                         // 256
    float* vb     = va + 256;                          // 256
    int*   deg    = (int*)(vb + 256);                  // N+1
    int*   rowptr = deg + M;                           // N+1
    int*   csum   = rowptr + M;                        // 256
    int*   coff   = csum + 256;                        // 256
    int*   srcbuf = coff + 256;                        // Epad
    int*   rankb  = srcbuf + Epad;                     // Epad
    unsigned* minenc = (unsigned*)(rankb + Epad);      // 64

    hipMemsetAsync(deg, 0, (size_t)M * 4, stream);
    hipMemsetAsync(minenc, 0xFF, 64 * 4, stream);

    int nb16 = (N + 15) / 16;
    int nb32 = (N + 31) / 32;
    int nb4 = (N + 3) / 4;
    int nbh = (Etot + 255) / 256;
    int nbz = 1568;                        // grid-stride; ~32 dsts/block, 100k atomicMin total

    pre_kernel<<<193, 256, 0, stream>>>(W1, W2, a_src2, a_dst2, W1s, W2s, va, vb);
    front_kernel<<<nb16 + nbh, 256, 0, stream>>>(x, W1s, a_src1, a_dst1, h1b, ssrc1, sdst1,
                                                 ei, deg, rankb, N, E, Etot, nb16);

    chunksum_kernel<<<nchunks, 256, 0, stream>>>(deg, csum, M);
    scanchunks_kernel<<<1, 256, 0, stream>>>(csum, coff, nchunks);
    rowptr_kernel<<<nchunks, 256, 0, stream>>>(deg, coff, rowptr, M);
    scatter_kernel<<<(Etot + 255) / 256, 256, 0, stream>>>(ei, rowptr, rankb, srcbuf, E, Etot);

    agg1_kernel<<<nb4, 256, 0, stream>>>(rowptr, srcbuf, ssrc1, sdst1, h1b, b1,
                                         va, vb, x2b, ssrc2, sdst2, N);
    gemmz_kernel<<<nb32, 256, 0, stream>>>(x2b, W2s, b2, z, N);
    aggz_kernel<<<nbz, 256, 0, stream>>>(rowptr, srcbuf, ssrc2, sdst2, z, minenc, N);
    decode_kernel<<<1, 64, 0, stream>>>(minenc, out);
}

// Round 14
// 290.813 us; speedup vs baseline: 1.7332x; 1.0716x over previous
//
#include <hip/hip_runtime.h>
#include <math.h>

typedef unsigned short ushort_t;
typedef __attribute__((ext_vector_type(8))) short bf16x8;
typedef __attribute__((ext_vector_type(4))) float f32x4;

// ---------- helpers ----------

__device__ inline unsigned fenc(float f) {
    unsigned u = __float_as_uint(f);
    return (u & 0x80000000u) ? ~u : (u | 0x80000000u);
}
__device__ inline float fdec(unsigned u) {
    return __uint_as_float((u & 0x80000000u) ? (u ^ 0x80000000u) : ~u);
}

__device__ inline float wrsum(float v) {
    #pragma unroll
    for (int m = 32; m; m >>= 1) v += __shfl_xor(v, m, 64);
    return v;
}
__device__ inline float lrelu(float x) { return x > 0.f ? x : 0.2f * x; }

__device__ inline ushort_t f2bf(float f) {
    unsigned u = __float_as_uint(f);
    u += 0x7FFFu + ((u >> 16) & 1u);      // round-to-nearest-even
    return (ushort_t)(u >> 16);
}
__device__ inline float bflo(unsigned u) { return __uint_as_float(u << 16); }
__device__ inline float bfhi(unsigned u) { return __uint_as_float(u & 0xFFFF0000u); }

// ---------- pre kernel: W swizzles + vab + deg/minenc init (memsets folded in) ----------
__global__ __launch_bounds__(256) void pre_kernel(const float* __restrict__ W1,
                                                  const float* __restrict__ W2,
                                                  const float* __restrict__ a_src2,
                                                  const float* __restrict__ a_dst2,
                                                  ushort_t* __restrict__ W1s,
                                                  ushort_t* __restrict__ W2s,
                                                  float* __restrict__ va,
                                                  float* __restrict__ vb,
                                                  int* __restrict__ deg,
                                                  unsigned* __restrict__ minenc,
                                                  int M) {
    int bid = blockIdx.x;
    int tid = threadIdx.x;
    if (bid < 128) {                       // W1 swizzle: 32768 elems
        int idx = bid * 256 + tid;
        int j = idx & 7;
        int lane = (idx >> 3) & 63;
        int ct = (idx >> 9) & 15;
        int kc = (idx >> 13) & 3;
        int k = kc * 32 + (lane >> 4) * 8 + j;
        int c = ct * 16 + (lane & 15);
        W1s[idx] = f2bf(W1[k * 256 + c]);
    } else if (bid < 192) {                // W2 swizzle: 16384 elems
        int idx = (bid - 128) * 256 + tid;
        int j = idx & 7;
        int lane = (idx >> 3) & 63;
        int ct = (idx >> 9) & 3;
        int kc = idx >> 11;
        int k = kc * 32 + (lane >> 4) * 8 + j;
        int c = ct * 16 + (lane & 15);
        W2s[idx] = f2bf(W2[k * 64 + c]);
    } else if (bid == 192) {               // vab + minenc init
        int k = tid;
        float sa = 0.f, sb = 0.f;
        #pragma unroll 8
        for (int c = 0; c < 64; c++) {
            float w = W2[k * 64 + c];
            sa += w * a_src2[c];
            sb += w * a_dst2[c];
        }
        va[k] = sa;
        vb[k] = sb;
        if (tid < 64) minenc[tid] = 0xFFFFFFFFu;
    } else {                               // deg zero
        int t = (bid - 193) * 256 + tid;
        if (t < M) deg[t] = 0;
    }
}

// ---------- front kernel: MFMA gemm1 (+scores1) merged with hist (+rank capture) ----------
__global__ __launch_bounds__(256) void front_kernel(const float* __restrict__ x,
                                                    const ushort_t* __restrict__ W1s,
                                                    const float* __restrict__ a_src,
                                                    const float* __restrict__ a_dst,
                                                    ushort_t* __restrict__ h1b,
                                                    float* __restrict__ ssrc,
                                                    float* __restrict__ sdst,
                                                    const int* __restrict__ ei,
                                                    int* __restrict__ deg,
                                                    int* __restrict__ rankb,
                                                    int N, int E, int Etot, int nb16) {
    __shared__ float ss[16 * 257];         // aliased: x staging first, D-tile after
    __shared__ float ps[256];
    int bid = blockIdx.x;
    int tid = threadIdx.x;

    if (bid >= nb16) {                     // ---- hist + rank ----
        int i = (bid - nb16) * 256 + tid;
        if (i < Etot) {
            int d = (i < E) ? ei[E + i] : (i - E);
            rankb[i] = atomicAdd(&deg[d], 1);
        }
        return;
    }

    // ---- stage x tile into LDS (coalesced; rows padded to 33 float4 = 132 floats) ----
    int base = bid * 16;
    {
        const float4* xv = (const float4*)(x + (size_t)base * 128);
        float4* xs4 = (float4*)ss;
        #pragma unroll
        for (int i = tid; i < 512; i += 256) {
            int row = i >> 5;              // 32 float4 per row
            float4 v = (base + row < N) ? xv[i] : make_float4(0.f, 0.f, 0.f, 0.f);
            xs4[row * 33 + (i & 31)] = v;
        }
    }
    __syncthreads();

    // ---- build A-fragments from LDS ----
    int lane = tid & 63, wv = tid >> 6;
    int m = lane & 15, q = lane >> 4;
    bf16x8 afrag[4];
    #pragma unroll
    for (int kc = 0; kc < 4; kc++) {
        const float* xp = ss + m * 132 + kc * 32 + q * 8;
        float4 xa = *(const float4*)xp;
        float4 xb = *(const float4*)(xp + 4);
        bf16x8 af;
        af[0] = (short)f2bf(xa.x); af[1] = (short)f2bf(xa.y);
        af[2] = (short)f2bf(xa.z); af[3] = (short)f2bf(xa.w);
        af[4] = (short)f2bf(xb.x); af[5] = (short)f2bf(xb.y);
        af[6] = (short)f2bf(xb.z); af[7] = (short)f2bf(xb.w);
        afrag[kc] = af;
    }
    __syncthreads();                       // xs dead; ss reused for D-tiles

    #pragma unroll
    for (int t = 0; t < 4; t++) {
        int ct = wv * 4 + t;
        f32x4 acc = {0.f, 0.f, 0.f, 0.f};
        #pragma unroll
        for (int kc = 0; kc < 4; kc++) {
            bf16x8 bfrag = *(const bf16x8*)(W1s + (((size_t)(kc * 16 + ct) * 64 + lane) << 3));
            acc = __builtin_amdgcn_mfma_f32_16x16x32_bf16(afrag[kc], bfrag, acc, 0, 0, 0);
        }
        #pragma unroll
        for (int reg = 0; reg < 4; reg++) {
            ss[(q * 4 + reg) * 257 + ct * 16 + m] = acc[reg];
        }
    }
    __syncthreads();

    // ---- dense h1b writes: thread (j, dd) packs 4 heads into one uint2 ----
    int dd = tid & 63, jj = tid >> 6;
    #pragma unroll
    for (int t2 = 0; t2 < 4; t2++) {
        int j = jj + t2 * 4;
        int n = base + j;
        if (n < N) {
            const float* row = ss + j * 257;
            unsigned p0 = (unsigned)f2bf(row[dd]) | ((unsigned)f2bf(row[64 + dd]) << 16);
            unsigned p1 = (unsigned)f2bf(row[128 + dd]) | ((unsigned)f2bf(row[192 + dd]) << 16);
            *(uint2*)(h1b + (size_t)n * 256 + dd * 4) = make_uint2(p0, p1);
        }
    }
    // ---- scores via partial sums (hh2-rotated) ----
    int j = tid & 15, hh2 = (tid >> 4) & 3, which = (tid >> 6) & 1, half = tid >> 7;
    const float* av = which ? a_dst : a_src;
    int cbase = hh2 * 64 + half * 32;
    float sum = 0.f;
    #pragma unroll
    for (int i = 0; i < 32; i++) {
        int ii = (i + 8 * hh2) & 31;
        sum += ss[j * 257 + cbase + ii] * av[cbase + ii];
    }
    ps[tid] = sum;
    __syncthreads();
    if (half == 0) {
        float tot = sum + ps[tid + 128];
        int n = base + j;
        if (n < N) (which ? sdst : ssrc)[n * 4 + hh2] = tot;
    }
}

// ---------- CSR scan chain ----------
__global__ __launch_bounds__(256) void chunksum_kernel(const int* __restrict__ deg,
                                                       int* __restrict__ csum, int M) {
    __shared__ int sm[256];
    int t = blockIdx.x * 256 + threadIdx.x;
    sm[threadIdx.x] = (t < M) ? deg[t] : 0;
    __syncthreads();
    for (int off = 128; off > 0; off >>= 1) {
        if (threadIdx.x < off) sm[threadIdx.x] += sm[threadIdx.x + off];
        __syncthreads();
    }
    if (threadIdx.x == 0) csum[blockIdx.x] = sm[0];
}

__global__ __launch_bounds__(256) void scanchunks_kernel(const int* __restrict__ csum,
                                                         int* __restrict__ coffset, int nchunks) {
    __shared__ int sm[256];
    int v = (threadIdx.x < nchunks) ? csum[threadIdx.x] : 0;
    sm[threadIdx.x] = v;
    __syncthreads();
    for (int off = 1; off < 256; off <<= 1) {
        int a = (threadIdx.x >= off) ? sm[threadIdx.x - off] : 0;
        __syncthreads();
        sm[threadIdx.x] += a;
        __syncthreads();
    }
    coffset[threadIdx.x] = sm[threadIdx.x] - v;
}

__global__ __launch_bounds__(256) void rowptr_kernel(const int* __restrict__ deg,
                                                     const int* __restrict__ coffset,
                                                     int* __restrict__ rowptr, int M) {
    __shared__ int sm[256];
    int t = blockIdx.x * 256 + threadIdx.x;
    int v = (t < M) ? deg[t] : 0;
    sm[threadIdx.x] = v;
    __syncthreads();
    for (int off = 1; off < 256; off <<= 1) {
        int a = (threadIdx.x >= off) ? sm[threadIdx.x - off] : 0;
        __syncthreads();
        sm[threadIdx.x] += a;
        __syncthreads();
    }
    if (t < M) rowptr[t] = coffset[blockIdx.x] + sm[threadIdx.x] - v;
}

// ---------- scatter (atomic-free via ranks) ----------
__global__ __launch_bounds__(256) void scatter_kernel(const int* __restrict__ ei,
                                                      const int* __restrict__ rowptr,
                                                      const int* __restrict__ rankb,
                                                      int* __restrict__ srcbuf, int E, int Etot) {
    int i = blockIdx.x * 256 + threadIdx.x;
    if (i >= Etot) return;
    int s, d;
    if (i < E) { s = ei[i]; d = ei[E + i]; } else { s = d = i - E; }
    srcbuf[rowptr[d] + rankb[i]] = s;
}

// ---------- layer-1 aggregation: plain-exp softmax, bf16 512B rows ----------
__global__ __launch_bounds__(256) void agg1_kernel(const int* __restrict__ rowptr,
                                                   const int* __restrict__ srcbuf,
                                                   const float* __restrict__ ssrc,
                                                   const float* __restrict__ sdst,
                                                   const ushort_t* __restrict__ h1b,
                                                   const float* __restrict__ b1,
                                                   const float* __restrict__ va,
                                                   const float* __restrict__ vb,
                                                   ushort_t* __restrict__ x2b,
                                                   float* __restrict__ ssrc2,
                                                   float* __restrict__ sdst2, int N) {
    __shared__ int    s_sh[4][64];
    __shared__ float4 w_sh[4][64];
    int lane = threadIdx.x & 63, w = threadIdx.x >> 6;
    int d = blockIdx.x * 4 + w;
    if (d >= N) return;
    int row = rowptr[d], end = rowptr[d + 1];
    float4 sd = *(const float4*)(sdst + d * 4);
    float l0 = 0.f, l1 = 0.f, l2 = 0.f, l3 = 0.f;
    float a0 = 0.f, a1 = 0.f, a2 = 0.f, a3 = 0.f;

    for (int base = row; base < end; base += 64) {
        int cnt = min(64, end - base);
        bool valid = lane < cnt;
        int s = valid ? srcbuf[base + lane] : 0;
        float4 ssv = *(const float4*)(ssrc + s * 4);
        float w0 = valid ? __expf(lrelu(ssv.x + sd.x)) : 0.f;
        float w1 = valid ? __expf(lrelu(ssv.y + sd.y)) : 0.f;
        float w2 = valid ? __expf(lrelu(ssv.z + sd.z)) : 0.f;
        float w3 = valid ? __expf(lrelu(ssv.w + sd.w)) : 0.f;
        l0 += wrsum(w0);  l1 += wrsum(w1);
        l2 += wrsum(w2);  l3 += wrsum(w3);
        s_sh[w][lane] = s;
        w_sh[w][lane] = make_float4(w0, w1, w2, w3);
        // wave-private LDS; lockstep wave, no barrier needed
        int cnt4 = (cnt + 3) & ~3;
        for (int j = 0; j < cnt4; j += 4) {
            int sj0 = s_sh[w][j], sj1 = s_sh[w][j + 1], sj2 = s_sh[w][j + 2], sj3 = s_sh[w][j + 3];
            float4 wj0 = w_sh[w][j], wj1 = w_sh[w][j + 1], wj2 = w_sh[w][j + 2], wj3 = w_sh[w][j + 3];
            uint2 u0 = *(const uint2*)(h1b + (size_t)sj0 * 256 + lane * 4);
            uint2 u1 = *(const uint2*)(h1b + (size_t)sj1 * 256 + lane * 4);
            uint2 u2 = *(const uint2*)(h1b + (size_t)sj2 * 256 + lane * 4);
            uint2 u3 = *(const uint2*)(h1b + (size_t)sj3 * 256 + lane * 4);
            a0 += wj0.x * bflo(u0.x); a1 += wj0.y * bfhi(u0.x);
            a2 += wj0.z * bflo(u0.y); a3 += wj0.w * bfhi(u0.y);
            a0 += wj1.x * bflo(u1.x); a1 += wj1.y * bfhi(u1.x);
            a2 += wj1.z * bflo(u1.y); a3 += wj1.w * bfhi(u1.y);
            a0 += wj2.x * bflo(u2.x); a1 += wj2.y * bfhi(u2.x);
            a2 += wj2.z * bflo(u2.y); a3 += wj2.w * bfhi(u2.y);
            a0 += wj3.x * bflo(u3.x); a1 += wj3.y * bfhi(u3.x);
            a2 += wj3.z * bflo(u3.y); a3 += wj3.w * bfhi(u3.y);
        }
    }
    float v0 = a0 / l0 + b1[lane];
    float v1 = a1 / l1 + b1[64 + lane];
    float v2 = a2 / l2 + b1[128 + lane];
    float v3 = a3 / l3 + b1[192 + lane];
    v0 = v0 > 0.f ? v0 : __expf(v0) - 1.f;
    v1 = v1 > 0.f ? v1 : __expf(v1) - 1.f;
    v2 = v2 > 0.f ? v2 : __expf(v2) - 1.f;
    v3 = v3 > 0.f ? v3 : __expf(v3) - 1.f;
    ushort_t* xp = x2b + (size_t)d * 256;
    xp[lane] = f2bf(v0); xp[64 + lane] = f2bf(v1);
    xp[128 + lane] = f2bf(v2); xp[192 + lane] = f2bf(v3);
    float sa = v0 * va[lane] + v1 * va[64 + lane] + v2 * va[128 + lane] + v3 * va[192 + lane];
    float sb = v0 * vb[lane] + v1 * vb[64 + lane] + v2 * vb[128 + lane] + v3 * vb[192 + lane];
    sa = wrsum(sa);
    sb = wrsum(sb);
    if (lane == 0) { ssrc2[d] = sa; sdst2[d] = sb; }
}

// ---------- gemmz via MFMA: z = x2b @ W2 + b2 (fp32, N x 64) ----------
__global__ __launch_bounds__(256) void gemmz_kernel(const ushort_t* __restrict__ x2b,
                                                    const ushort_t* __restrict__ W2s,
                                                    const float* __restrict__ b2,
                                                    float* __restrict__ z, int N) {
    int base = blockIdx.x * 32;
    int tid = threadIdx.x;
    int lane = tid & 63, wv = tid >> 6;
    int m = lane & 15, q = lane >> 4;
    int c = wv * 16 + m;
    float bc = b2[c];

    #pragma unroll
    for (int h = 0; h < 2; h++) {
        int rbase = base + h * 16;
        bool rowok = (rbase + m) < N;
        const ushort_t* xrow = x2b + (size_t)(rbase + m) * 256;
        f32x4 acc = {0.f, 0.f, 0.f, 0.f};
        #pragma unroll
        for (int kc = 0; kc < 8; kc++) {
            bf16x8 af = {0, 0, 0, 0, 0, 0, 0, 0};
            if (rowok) af = *(const bf16x8*)(xrow + kc * 32 + q * 8);
            bf16x8 bf = *(const bf16x8*)(W2s + (((size_t)(kc * 4 + wv) * 64 + lane) << 3));
            acc = __builtin_amdgcn_mfma_f32_16x16x32_bf16(af, bf, acc, 0, 0, 0);
        }
        #pragma unroll
        for (int reg = 0; reg < 4; reg++) {
            int n = rbase + q * 4 + reg;
            if (n < N) z[(size_t)n * 64 + c] = acc[reg] + bc;
        }
    }
}

// ---------- layer-2 aggregation over z (256B fp32 rows) + fused global min ----------
__global__ __launch_bounds__(256) void aggz_kernel(const int* __restrict__ rowptr,
                                                   const int* __restrict__ srcbuf,
                                                   const float* __restrict__ ssrc,
                                                   const float* __restrict__ sdst,
                                                   const float* __restrict__ z,
                                                   unsigned* __restrict__ minenc, int N) {
    __shared__ int   s_sh[4][64];
    __shared__ float w_sh[4][64];
    __shared__ float sm[256];
    int lane = threadIdx.x & 63, w = threadIdx.x >> 6;
    float minv = INFINITY;

    for (int d0 = blockIdx.x * 4; d0 < N; d0 += gridDim.x * 4) {
        int d = d0 + w;
        if (d < N) {
            int row = rowptr[d], end = rowptr[d + 1];
            float sdv = sdst[d];
            float l = 0.f;
            float a0 = 0.f, a1 = 0.f, a2 = 0.f, a3 = 0.f;
            for (int base = row; base < end; base += 64) {
                int cnt = min(64, end - base);
                bool valid = lane < cnt;
                int s = valid ? srcbuf[base + lane] : 0;
                float wt = valid ? __expf(lrelu(ssrc[s] + sdv)) : 0.f;
                l += wrsum(wt);
                s_sh[w][lane] = s;
                w_sh[w][lane] = wt;
                // wave-private LDS; lockstep wave
                int cnt4 = (cnt + 3) & ~3;
                for (int j = 0; j < cnt4; j += 4) {
                    int sj0 = s_sh[w][j], sj1 = s_sh[w][j + 1];
                    int sj2 = s_sh[w][j + 2], sj3 = s_sh[w][j + 3];
                    float wj0 = w_sh[w][j], wj1 = w_sh[w][j + 1];
                    float wj2 = w_sh[w][j + 2], wj3 = w_sh[w][j + 3];
                    float z0 = z[(size_t)sj0 * 64 + lane];
                    float z1 = z[(size_t)sj1 * 64 + lane];
                    float z2 = z[(size_t)sj2 * 64 + lane];
                    float z3 = z[(size_t)sj3 * 64 + lane];
                    a0 += wj0 * z0; a1 += wj1 * z1;
                    a2 += wj2 * z2; a3 += wj3 * z3;
                }
            }
            float out = ((a0 + a1) + (a2 + a3)) / l;   // b2 already folded into z
            minv = fminf(minv, out);
        }
    }
    sm[threadIdx.x] = minv;
    __syncthreads();
    if (w == 0) {
        float v = fminf(fminf(sm[lane], sm[64 + lane]), fminf(sm[128 + lane], sm[192 + lane]));
        atomicMin(&minenc[lane], fenc(v));
    }
}

__global__ void decode_kernel(const unsigned* __restrict__ minenc, float* __restrict__ out) {
    int d = threadIdx.x;
    if (d < 64) out[d] = fdec(minenc[d]);
}

// ---------- launch ----------
extern "C" void kernel_launch(void* const* d_in, const int* in_sizes, int n_in,
                              void* d_out, int out_size, void* d_ws, size_t ws_size,
                              hipStream_t stream) {
    const float* x      = (const float*)d_in[0];
    const int*   ei     = (const int*)d_in[1];
    const float* W1     = (const float*)d_in[2];
    const float* a_src1 = (const float*)d_in[3];
    const float* a_dst1 = (const float*)d_in[4];
    const float* b1     = (const float*)d_in[5];
    const float* W2     = (const float*)d_in[6];
    const float* a_src2 = (const float*)d_in[7];
    const float* a_dst2 = (const float*)d_in[8];
    const float* b2     = (const float*)d_in[9];
    float* out = (float*)d_out;

    const int N = in_sizes[0] / 128;
    const int E = in_sizes[1] / 2;
    const int Etot = E + N;
    const int Epad = Etot + 64;
    const int M = N + 1;
    const int nchunks = (M + 255) / 256;   // <= 256 for N <= ~65k

    // workspace layout (4-byte words; N divisible by 4 keeps 16B alignment)
    float* ws = (float*)d_ws;
    ushort_t* h1b = (ushort_t*)ws;                     // N*256 bf16 = N*128 words
    ushort_t* x2b = (ushort_t*)(ws + (size_t)N * 128); // N*256 bf16
    float* z      = ws + (size_t)N * 256;              // N*64 fp32
    ushort_t* W1s = (ushort_t*)(ws + (size_t)N * 320); // 32768 bf16 = 16384 words
    ushort_t* W2s = (ushort_t*)(ws + (size_t)N * 320 + 16384); // 16384 bf16 = 8192 words
    float* ssrc1  = ws + (size_t)N * 320 + 24576;      // 4N (16B aligned)
    float* sdst1  = ssrc1 + (size_t)N * 4;             // 4N
    float* ssrc2  = sdst1 + (size_t)N * 4;             // N
    float* sdst2  = ssrc2 + N;                         // N
    float* va     = sdst2 + N;                         // 256
    float* vb     = va + 256;                          // 256
    int*   deg    = (int*)(vb + 256);                  // N+1
    int*   rowptr = deg + M;                           // N+1
    int*   csum   = rowptr + M;                        // 256
    int*   coff   = csum + 256;                        // 256
    int*   srcbuf = coff + 256;                        // Epad
    int*   rankb  = srcbuf + Epad;                     // Epad
    unsigned* minenc = (unsigned*)(rankb + Epad);      // 64

    int nb16 = (N + 15) / 16;
    int nb32 = (N + 31) / 32;
    int nb4 = (N + 3) / 4;
    int nbh = (Etot + 255) / 256;
    int nbz = 1568;                        // grid-stride; ~32 dsts/block
    int nbdeg = (M + 255) / 256;

    pre_kernel<<<193 + nbdeg, 256, 0, stream>>>(W1, W2, a_src2, a_dst2, W1s, W2s,
                                                va, vb, deg, minenc, M);
    front_kernel<<<nb16 + nbh, 256, 0, stream>>>(x, W1s, a_src1, a_dst1, h1b, ssrc1, sdst1,
                                                 ei, deg, rankb, N, E, Etot, nb16);

    chunksum_kernel<<<nchunks, 256, 0, stream>>>(deg, csum, M);
    scanchunks_kernel<<<1, 256, 0, stream>>>(csum, coff, nchunks);
    rowptr_kernel<<<nchunks, 256, 0, stream>>>(deg, coff, rowptr, M);
    scatter_kernel<<<(Etot + 255) / 256, 256, 0, stream>>>(ei, rowptr, rankb, srcbuf, E, Etot);

    agg1_kernel<<<nb4, 256, 0, stream>>>(rowptr, srcbuf, ssrc1, sdst1, h1b, b1,
                                         va, vb, x2b, ssrc2, sdst2, N);
    gemmz_kernel<<<nb32, 256, 0, stream>>>(x2b, W2s, b2, z, N);
    aggz_kernel<<<nbz, 256, 0, stream>>>(rowptr, srcbuf, ssrc2, sdst2, z, minenc, N);
    decode_kernel<<<1, 64, 0, stream>>>(minenc, out);
}